// Round 10
// baseline (244.605 us; speedup 1.0000x reference)
//
#include <hip/hip_runtime.h>

typedef unsigned short u16;
typedef unsigned int u32;
typedef float f32x4 __attribute__((ext_vector_type(4)));
typedef float f32x16 __attribute__((ext_vector_type(16)));
typedef __bf16 bf16x8 __attribute__((ext_vector_type(8)));
typedef u16 u16x4v __attribute__((ext_vector_type(4)));
typedef u32 u32x2 __attribute__((ext_vector_type(2)));
typedef u32 u32x4 __attribute__((ext_vector_type(4)));

#define NHEAD 12
#define NN 2048
#define CC 768

#define GLOBAL_AS __attribute__((address_space(1)))
#define LDS_AS __attribute__((address_space(3)))

__device__ __forceinline__ u16 tobf(float f) {
  __bf16 h = (__bf16)f;
  return __builtin_bit_cast(u16, h);
}
__device__ __forceinline__ float bf2f(u16 h) {
  u32 u = ((u32)h) << 16;
  return __builtin_bit_cast(float, u);
}
__device__ __forceinline__ u32 cvtpk(float lo, float hi) {
  u32 r;
  asm("v_cvt_pk_bf16_f32 %0, %1, %2" : "=v"(r) : "v"(lo), "v"(hi));
  return r;
}
__device__ __forceinline__ void plswap(u32& a, u32& b) {
  asm volatile("v_permlane32_swap_b32 %0, %1" : "+v"(a), "+v"(b));
}
__device__ __forceinline__ void plswapf(float& a, float& b) {
  asm volatile("v_permlane32_swap_b32 %0, %1" : "+v"(a), "+v"(b));
}
// exact-erf GELU via A&S 7.1.26 (|err| <= 1.5e-7, far below bf16 ulp)
__device__ __forceinline__ float gelu_erf(float v) {
  float y = fabsf(v) * 0.70710678118654752f;
  float t = __builtin_amdgcn_rcpf(fmaf(0.3275911f, y, 1.f));
  float p = fmaf(1.061405429f, t, -1.453152027f);
  p = fmaf(p, t, 1.421413741f);
  p = fmaf(p, t, -0.284496736f);
  p = fmaf(p, t, 0.254829592f);
  p = p * t;
  float e = __builtin_amdgcn_exp2f(-y * y * 1.44269504f);
  float er = fmaf(-p, e, 1.f);
  er = (v < 0.f) ? -er : er;
  return 0.5f * v * (1.f + er);
}

// ---------------- fused fp32 -> bf16 convert of all 4 weights ----------------
#define N4_QKV 442368
#define N4_PROJ 147456
#define N4_FC 589824
__global__ __launch_bounds__(256) void cvt4_kernel(
    const float* __restrict__ a, const float* __restrict__ b,
    const float* __restrict__ c, const float* __restrict__ d,
    u16* __restrict__ oa, u16* __restrict__ ob, u16* __restrict__ oc,
    u16* __restrict__ od) {
  int i = blockIdx.x * 256 + threadIdx.x;
  const float* src;
  u16* dst;
  if (i < N4_QKV) {
    src = a; dst = oa;
  } else if (i < N4_QKV + N4_PROJ) {
    i -= N4_QKV; src = b; dst = ob;
  } else if (i < N4_QKV + N4_PROJ + N4_FC) {
    i -= N4_QKV + N4_PROJ; src = c; dst = oc;
  } else {
    i -= N4_QKV + N4_PROJ + N4_FC; src = d; dst = od;
    if (i >= N4_FC) return;
  }
  float4 v = ((const float4*)src)[i];
  u16x4v o = {tobf(v.x), tobf(v.y), tobf(v.z), tobf(v.w)};
  ((u16x4v*)dst)[i] = o;
}

// ---------------- LayerNorm: f32 in -> bf16 out (wave per row) ----------------
__global__ __launch_bounds__(256) void ln_kernel(const float* __restrict__ x,
                                                 const float* __restrict__ gw,
                                                 const float* __restrict__ bw,
                                                 u16* __restrict__ out) {
  int row = blockIdx.x * 4 + (threadIdx.x >> 6);
  int lane = threadIdx.x & 63;
  const float* xr = x + (size_t)row * CC + lane * 12;
  float v[12];
  *(float4*)&v[0] = *(const float4*)(xr + 0);
  *(float4*)&v[4] = *(const float4*)(xr + 4);
  *(float4*)&v[8] = *(const float4*)(xr + 8);
  float s = 0.f, sq = 0.f;
#pragma unroll
  for (int j = 0; j < 12; ++j) { s += v[j]; sq += v[j] * v[j]; }
#pragma unroll
  for (int o = 1; o < 64; o <<= 1) { s += __shfl_xor(s, o); sq += __shfl_xor(sq, o); }
  float mean = s * (1.f / CC);
  float var = sq * (1.f / CC) - mean * mean;
  float rs = rsqrtf(var + 1e-5f);
  u16 ob[12];
#pragma unroll
  for (int j = 0; j < 12; ++j) {
    int c = lane * 12 + j;
    ob[j] = tobf((v[j] - mean) * rs * gw[c] + bw[c]);
  }
  u32* orow = (u32*)(out + (size_t)row * CC + lane * 12);
#pragma unroll
  for (int j = 0; j < 6; ++j) orow[j] = (u32)ob[2 * j] | ((u32)ob[2 * j + 1] << 16);
}

// ---------------- bf16 MFMA GEMM: C[M,N] = A[M,K] @ Bw[N,K]^T ----------------
// 2-phase pipelined: dbuf LDS, stage(t+1) issued before compute(t), raw
// s_barrier + counted vmcnt (never 0 mid-loop). XCD-aware bijective swizzle.
template <int BM, int OB, int HASB, int ACT, int RES>
__global__ __launch_bounds__(256) void gemm_kernel(
    const u16* __restrict__ A, const u16* __restrict__ Bw,
    const float* __restrict__ bias, const float* __restrict__ res,
    void* __restrict__ Cout, int M, int N, int K) {
  constexpr int MW = BM / 2;
  constexpr int MF = MW / 16;
  __shared__ __align__(16) u16 Alds[2][BM * 64];
  __shared__ __align__(16) u16 Blds[2][128 * 64];
  const int tid = threadIdx.x;
  const int lane = tid & 63, wave = tid >> 6;
  const int l15 = lane & 15, g = lane >> 4;
  const int nx = gridDim.x;
  const int flat = blockIdx.y * nx + blockIdx.x;
  const int cpx = (nx * gridDim.y) >> 3;
  const int swz = (flat & 7) * cpx + (flat >> 3);
  const int bm = (swz % nx) * BM, bn = (swz / nx) * 128;
  const int wm = (wave >> 1) * MW, wn = (wave & 1) * 64;
  f32x4 acc[MF][4] = {};

  auto stage = [&](int buf, int kt) {
#pragma unroll
    for (int i = 0; i < BM / 32; ++i) {
      int ob_ = i * 4096 + wave * 1024;
      int lb = ob_ + lane * 16;
      int row = lb >> 7;
      int cb = (lb & 127) ^ ((row & 7) << 4);
      const u16* sa = A + (size_t)(bm + row) * K + kt + (cb >> 1);
      __builtin_amdgcn_global_load_lds((const GLOBAL_AS void*)sa,
                                       (LDS_AS void*)(&Alds[buf][0] + (ob_ >> 1)), 16, 0, 0);
    }
#pragma unroll
    for (int i = 0; i < 4; ++i) {
      int ob_ = i * 4096 + wave * 1024;
      int lb = ob_ + lane * 16;
      int row = lb >> 7;
      int cb = (lb & 127) ^ ((row & 7) << 4);
      const u16* sb = Bw + (size_t)(bn + row) * K + kt + (cb >> 1);
      __builtin_amdgcn_global_load_lds((const GLOBAL_AS void*)sb,
                                       (LDS_AS void*)(&Blds[buf][0] + (ob_ >> 1)), 16, 0, 0);
    }
  };

  const int nt = K >> 6;
  stage(0, 0);
#pragma unroll 1
  for (int t = 0; t < nt; ++t) {
    const int cur = t & 1;
    if (t + 1 < nt) {
      stage(cur ^ 1, (t + 1) * 64);
      // wait for tile t's loads only; tile t+1's (BM/32 + 4) stay in flight
      if constexpr (BM == 128) {
        asm volatile("s_waitcnt vmcnt(8)" ::: "memory");
      } else {
        asm volatile("s_waitcnt vmcnt(6)" ::: "memory");
      }
    } else {
      asm volatile("s_waitcnt vmcnt(0)" ::: "memory");
    }
    __builtin_amdgcn_sched_barrier(0);
    __builtin_amdgcn_s_barrier();
    __builtin_amdgcn_sched_barrier(0);
#pragma unroll
    for (int ks = 0; ks < 2; ++ks) {
      bf16x8 af[MF], bfr[4];
#pragma unroll
      for (int mi = 0; mi < MF; ++mi) {
        int row = wm + mi * 16 + l15;
        int cb = (ks * 64 + g * 16) ^ ((row & 7) << 4);
        af[mi] = *(const bf16x8*)&Alds[cur][row * 64 + (cb >> 1)];
      }
#pragma unroll
      for (int ni = 0; ni < 4; ++ni) {
        int row = wn + ni * 16 + l15;
        int cb = (ks * 64 + g * 16) ^ ((row & 7) << 4);
        bfr[ni] = *(const bf16x8*)&Blds[cur][row * 64 + (cb >> 1)];
      }
#pragma unroll
      for (int mi = 0; mi < MF; ++mi)
#pragma unroll
        for (int ni = 0; ni < 4; ++ni)
          acc[mi][ni] = __builtin_amdgcn_mfma_f32_16x16x32_bf16(af[mi], bfr[ni],
                                                                acc[mi][ni], 0, 0, 0);
    }
    asm volatile("s_waitcnt lgkmcnt(0)" ::: "memory");
    __builtin_amdgcn_sched_barrier(0);
    __builtin_amdgcn_s_barrier();
    __builtin_amdgcn_sched_barrier(0);
  }
#pragma unroll
  for (int mi = 0; mi < MF; ++mi) {
#pragma unroll
    for (int ni = 0; ni < 4; ++ni) {
      int col = bn + wn + ni * 16 + l15;
      float bs = HASB ? bias[col] : 0.f;
#pragma unroll
      for (int r = 0; r < 4; ++r) {
        int rowm = bm + wm + mi * 16 + g * 4 + r;
        float v = acc[mi][ni][r] + bs;
        if (ACT) v = gelu_erf(v);
        if (RES) v += res[(size_t)rowm * N + col];
        if (OB)
          ((u16*)Cout)[(size_t)rowm * N + col] = tobf(v);
        else
          ((float*)Cout)[(size_t)rowm * N + col] = v;
      }
    }
  }
}

// ---------------- Vsum: vs[q4][bh][d] = partial sums of V (ALL keys) ---------
__global__ __launch_bounds__(256) void vsum_kernel(const u16* __restrict__ qkv,
                                                   float* __restrict__ vs) {
  int bh = blockIdx.x, q4 = blockIdx.y;
  int b = bh / NHEAD, h = bh % NHEAD;
  int d = threadIdx.x & 63, part = threadIdx.x >> 6;
  float s = 0.f;
  for (int n = q4 * 512 + part; n < q4 * 512 + 512; n += 4)
    s += bf2f(qkv[(size_t)(b * NN + n) * 2304 + 2 * CC + h * 64 + d]);
  __shared__ float red[256];
  red[threadIdx.x] = s;
  __syncthreads();
  if (threadIdx.x < 64) {
    float t = red[threadIdx.x] + red[threadIdx.x + 64] + red[threadIdx.x + 128] +
              red[threadIdx.x + 192];
    vs[q4 * (24 * 64) + bh * 64 + threadIdx.x] = t;
  }
}

// ---------------- policy compaction: deterministic prefix-scan ---------------
__global__ __launch_bounds__(256) void scan_kernel(const float* __restrict__ policy,
                                                   int* __restrict__ ncbuf,
                                                   int* __restrict__ idxbuf) {
  int b = blockIdx.x, tid = threadIdx.x;
  float pv[8];
  *(float4*)&pv[0] = *(const float4*)&policy[b * NN + tid * 8];
  *(float4*)&pv[4] = *(const float4*)&policy[b * NN + tid * 8 + 4];
  int cnt = 0;
#pragma unroll
  for (int j = 0; j < 8; ++j) cnt += (pv[j] != 0.f) ? 1 : 0;
  __shared__ int sc[256];
  sc[tid] = cnt;
  __syncthreads();
  for (int off = 1; off < 256; off <<= 1) {
    int v = sc[tid];
    int add = (tid >= off) ? sc[tid - off] : 0;
    __syncthreads();
    sc[tid] = v + add;
    __syncthreads();
  }
  int base = sc[tid] - cnt;
#pragma unroll
  for (int j = 0; j < 8; ++j) {
    if (pv[j] != 0.f) idxbuf[b * NN + base++] = tid * 8 + j;
  }
  if (tid == 255) ncbuf[b] = sc[255];
}

// ---------------- gather compacted K,V rows (zero the pad tile) --------------
__global__ __launch_bounds__(256) void gather_kernel(const u16* __restrict__ qkv,
                                                     const int* __restrict__ ncbuf,
                                                     const int* __restrict__ idxbuf,
                                                     u16* __restrict__ ckv) {
  int b = blockIdx.y;
  int nc = ncbuf[b];
  int ncp = (nc + 127) & ~127;
  int c = blockIdx.x * 256 + threadIdx.x;  // 16B chunk id; 192 chunks/row
  int j = c / 192, col = (c % 192) * 8;
  if (j >= ncp) return;
  uint4 val = {0, 0, 0, 0};
  if (j < nc) {
    int src = idxbuf[b * NN + j];
    val = *(const uint4*)&qkv[(size_t)(b * NN + src) * 2304 + CC + col];
  }
  *(uint4*)&ckv[(size_t)(b * NN + j) * 1536 + col] = val;
}

// ---------------- Flash attention on COMPACTED keys --------------------------
#define SCL2E 0.18033688f /* 0.125 * log2(e) */
#define TRRD(dst, addr, OFF) \
  asm volatile("ds_read_b64_tr_b16 %0, %1 offset:" OFF : "=v"(dst) : "v"(addr))

__global__ __launch_bounds__(256) void attn32_kernel(const u16* __restrict__ qkv,
                                                     const u16* __restrict__ ckv,
                                                     const int* __restrict__ ncbuf,
                                                     float* __restrict__ partO,
                                                     float* __restrict__ partlm) {
  __shared__ __align__(16) u16 Klds[2][4096];  // [key][d] XOR-swizzled rows
  __shared__ __align__(16) u16 Vlds[2][4096];  // subtiled for tr-reads
  __shared__ float alf[4][32];
  const int bh = blockIdx.y, b = bh / NHEAD, h = bh % NHEAD;
  const int qt = blockIdx.x >> 1, half = blockIdx.x & 1;
  const int tid = threadIdx.x, lane = tid & 63, w = tid >> 6;
  const int l31 = lane & 31, hp = lane >> 5, b4 = (lane >> 4) & 1;
  const int q0 = qt * 128 + w * 32;
  const int nc = ncbuf[b];
  const int ncp = (nc + 127) & ~127;
  const int nh = ncp >> 1;      // keys per half (multiple of 64)
  const int nt = nh >> 6;       // 64-key tiles per half
  const int kv0 = half * nh;
  const size_t adv = (size_t)64 * 1536;

  bf16x8 qf0, qf1, qf2, qf3;
  {
    const u16* qp = qkv + (size_t)(b * NN + q0 + l31) * 2304 + h * 64 + 8 * hp;
#pragma unroll
    for (int ds = 0; ds < 4; ++ds) {
      bf16x8 r = *(const bf16x8*)(qp + ds * 16);
      bf16x8 o;
#pragma unroll
      for (int j = 0; j < 8; ++j) o[j] = (__bf16)((float)r[j] * SCL2E);
      if (ds == 0) qf0 = o; else if (ds == 1) qf1 = o; else if (ds == 2) qf2 = o; else qf3 = o;
    }
  }

  const u16* ksrc[2];
  const u16* vsrcp[2];
#pragma unroll
  for (int c = 0; c < 2; ++c) {
    int lb = c * 4096 + w * 1024 + lane * 16;
    int row = lb >> 7;
    int cb = (lb & 127) ^ ((row & 7) << 4);
    ksrc[c] = ckv + (size_t)(b * NN + kv0 + row) * 1536 + h * 64 + (cb >> 1);
    int idx0 = (c * 256 + w * 64 + lane) * 8;
    int s0 = idx0 & 15, jj = (idx0 >> 4) & 3, b4v = (idx0 >> 6) & 1,
        pv = (idx0 >> 7) & 1, hv = (idx0 >> 8) & 1, dtv = (idx0 >> 9) & 1,
        mkv = (idx0 >> 10) & 3;
    int key = mkv * 16 + 8 * hv + 4 * pv + jj;
    int d0 = dtv * 32 + 16 * b4v + s0;
    vsrcp[c] = ckv + (size_t)(b * NN + kv0 + key) * 1536 + CC + h * 64 + d0;
  }
  auto stage = [&](int buf) {
#pragma unroll
    for (int c = 0; c < 2; ++c) {
      __builtin_amdgcn_global_load_lds((const GLOBAL_AS void*)ksrc[c],
                                       (LDS_AS void*)&Klds[buf][c * 2048 + w * 512], 16, 0, 0);
      __builtin_amdgcn_global_load_lds((const GLOBAL_AS void*)vsrcp[c],
                                       (LDS_AS void*)&Vlds[buf][c * 2048 + w * 512], 16, 0, 0);
      ksrc[c] += adv; vsrcp[c] += adv;
    }
  };

  stage(0);
  __syncthreads();

  float m_cur = -3.0e38f, m_true = -3.0e38f, l_run = 0.f;
  f32x16 accd[2] = {};
  const u32 vbase = (u32)(uintptr_t)(LDS_AS u16*)&Vlds[0][0] +
                    (u32)(2 * (lane & 15) + 128 * b4 + 512 * hp);

#pragma unroll 1
  for (int t = 0; t < nt; ++t) {
    const int cur = t & 1;
    if (t < nt - 1) stage(cur ^ 1);

    f32x16 sv0, sv1;
    {
      bf16x8 kf[4];
#pragma unroll
      for (int ds = 0; ds < 4; ++ds) {
        int row = l31;
        int cb = (32 * ds + 16 * hp) ^ ((row & 7) << 4);
        kf[ds] = *(const bf16x8*)((const char*)&Klds[cur][0] + row * 128 + cb);
      }
      f32x16 a = {};
      a = __builtin_amdgcn_mfma_f32_32x32x16_bf16(kf[0], qf0, a, 0, 0, 0);
      a = __builtin_amdgcn_mfma_f32_32x32x16_bf16(kf[1], qf1, a, 0, 0, 0);
      a = __builtin_amdgcn_mfma_f32_32x32x16_bf16(kf[2], qf2, a, 0, 0, 0);
      a = __builtin_amdgcn_mfma_f32_32x32x16_bf16(kf[3], qf3, a, 0, 0, 0);
      sv0 = a;
    }
    {
      bf16x8 kf[4];
#pragma unroll
      for (int ds = 0; ds < 4; ++ds) {
        int row = 32 + l31;
        int cb = (32 * ds + 16 * hp) ^ ((row & 7) << 4);
        kf[ds] = *(const bf16x8*)((const char*)&Klds[cur][0] + row * 128 + cb);
      }
      f32x16 a = {};
      a = __builtin_amdgcn_mfma_f32_32x32x16_bf16(kf[0], qf0, a, 0, 0, 0);
      a = __builtin_amdgcn_mfma_f32_32x32x16_bf16(kf[1], qf1, a, 0, 0, 0);
      a = __builtin_amdgcn_mfma_f32_32x32x16_bf16(kf[2], qf2, a, 0, 0, 0);
      a = __builtin_amdgcn_mfma_f32_32x32x16_bf16(kf[3], qf3, a, 0, 0, 0);
      sv1 = a;
    }

    u32x2 tr[4][2][2];
    {
      u32 vab = vbase + (u32)(cur * 8192);
      TRRD(tr[0][0][0], vab, "0");    TRRD(tr[0][0][1], vab, "256");
      TRRD(tr[0][1][0], vab, "1024"); TRRD(tr[0][1][1], vab, "1280");
      TRRD(tr[1][0][0], vab, "2048"); TRRD(tr[1][0][1], vab, "2304");
      TRRD(tr[1][1][0], vab, "3072"); TRRD(tr[1][1][1], vab, "3328");
      TRRD(tr[2][0][0], vab, "4096"); TRRD(tr[2][0][1], vab, "4352");
      TRRD(tr[3][0][0], vab, "6144"); TRRD(tr[3][0][1], vab, "6400");
      TRRD(tr[2][1][0], vab, "5120"); TRRD(tr[2][1][1], vab, "5376");
      TRRD(tr[3][1][0], vab, "7168"); TRRD(tr[3][1][1], vab, "7424");
    }

    float ta = fmaxf(fmaxf(sv0[0], sv0[1]), sv0[2]);
    float tb = fmaxf(fmaxf(sv0[3], sv0[4]), sv0[5]);
    float tc = fmaxf(fmaxf(sv0[6], sv0[7]), sv0[8]);
    float td = fmaxf(fmaxf(sv0[9], sv0[10]), sv0[11]);
    float te = fmaxf(fmaxf(sv0[12], sv0[13]), sv0[14]);
    float tf = fmaxf(fmaxf(sv0[15], sv1[0]), sv1[1]);
    float tg = fmaxf(fmaxf(sv1[2], sv1[3]), sv1[4]);
    float th = fmaxf(fmaxf(sv1[5], sv1[6]), sv1[7]);
    float ti = fmaxf(fmaxf(sv1[8], sv1[9]), sv1[10]);
    float tj = fmaxf(fmaxf(sv1[11], sv1[12]), sv1[13]);
    float tk = fmaxf(sv1[14], sv1[15]);
    float tmax = fmaxf(fmaxf(fmaxf(fmaxf(ta, tb), fmaxf(tc, td)),
                             fmaxf(fmaxf(te, tf), fmaxf(tg, th))),
                       fmaxf(fmaxf(ti, tj), tk));
    {
      float t1 = tmax, t2 = tmax;
      plswapf(t1, t2);
      tmax = fmaxf(t1, t2);
    }
    m_true = fmaxf(m_true, tmax);
    const bool defer = __all(tmax <= m_cur + 8.f);
    const float m_new = defer ? m_cur : fmaxf(m_cur, tmax);

    const int thr = nc - (kv0 + t * 64);
    float ev[32];
#pragma unroll
    for (int kt = 0; kt < 2; ++kt) {
#pragma unroll
      for (int i = 0; i < 4; ++i) {
#pragma unroll
        for (int rq = 0; rq < 4; ++rq) {
          int r = 4 * i + rq;
          int kidx = kt * 32 + 8 * i + 4 * hp + rq;
          float sval = kt ? sv1[r] : sv0[r];
          float e = __builtin_amdgcn_exp2f(sval - m_new);
          ev[kt * 16 + r] = (kidx < thr) ? e : 0.f;
        }
      }
    }
    u32 wv[16];
#pragma unroll
    for (int j = 0; j < 16; ++j) wv[j] = cvtpk(ev[2 * j], ev[2 * j + 1]);
    float ps[16];
#pragma unroll
    for (int j = 0; j < 16; ++j)
      ps[j] = __builtin_bit_cast(float, wv[j] << 16) +
              __builtin_bit_cast(float, wv[j] & 0xffff0000u);
#pragma unroll
    for (int s = 8; s > 0; s >>= 1)
#pragma unroll
      for (int j = 0; j < s; ++j) ps[j] += ps[j + s];
    float psum = ps[0];
    {
      float s1 = psum, s2 = psum;
      plswapf(s1, s2);
      psum = s1 + s2;
    }
    if (!defer) {
      float alpha = __builtin_amdgcn_exp2f(m_cur - m_new);
      l_run = l_run * alpha + psum;
      m_cur = m_new;
      if (lane < 32) alf[w][lane] = alpha;
      float4 aq0 = *(const float4*)&alf[w][4 * hp];
      float4 aq1 = *(const float4*)&alf[w][8 + 4 * hp];
      float4 aq2 = *(const float4*)&alf[w][16 + 4 * hp];
      float4 aq3 = *(const float4*)&alf[w][24 + 4 * hp];
#pragma unroll
      for (int dt = 0; dt < 2; ++dt) {
#pragma unroll
        for (int rq = 0; rq < 4; ++rq) {
          accd[dt][0 + rq] *= ((const float*)&aq0)[rq];
          accd[dt][4 + rq] *= ((const float*)&aq1)[rq];
          accd[dt][8 + rq] *= ((const float*)&aq2)[rq];
          accd[dt][12 + rq] *= ((const float*)&aq3)[rq];
        }
      }
    } else {
      l_run += psum;
    }

    u32 PK[4][4];
#pragma unroll
    for (int mk = 0; mk < 4; ++mk) {
      int bw_ = 8 * (mk >> 1) + 4 * (mk & 1);
      PK[mk][0] = wv[bw_ + 0];
      PK[mk][1] = wv[bw_ + 1];
      PK[mk][2] = wv[bw_ + 2];
      PK[mk][3] = wv[bw_ + 3];
      plswap(PK[mk][2], PK[mk][0]);
      plswap(PK[mk][3], PK[mk][1]);
    }

    asm volatile("s_waitcnt lgkmcnt(0)" ::: "memory");
    __builtin_amdgcn_sched_barrier(0);

#pragma unroll
    for (int mk = 0; mk < 4; ++mk) {
      u32x4 pk4 = {PK[mk][0], PK[mk][1], PK[mk][2], PK[mk][3]};
      bf16x8 pf = __builtin_bit_cast(bf16x8, pk4);
#pragma unroll
      for (int dt = 0; dt < 2; ++dt) {
        u32x4 vv = {tr[mk][dt][0].x, tr[mk][dt][0].y, tr[mk][dt][1].x, tr[mk][dt][1].y};
        bf16x8 vf = __builtin_bit_cast(bf16x8, vv);
        accd[dt] = __builtin_amdgcn_mfma_f32_32x32x16_bf16(pf, vf, accd[dt], 0, 0, 0);
      }
    }
    __syncthreads();
  }

  float sr = __builtin_amdgcn_exp2f(m_cur - m_true);
  if (lane < 32) {
    alf[w][lane] = sr;
    float2 lm = {l_run * sr, m_true};
    *(float2*)&partlm[2 * ((size_t)(half * 24 + bh) * 2048 + q0 + lane)] = lm;
  }
  float4 sq0 = *(const float4*)&alf[w][4 * hp];
  float4 sq1 = *(const float4*)&alf[w][8 + 4 * hp];
  float4 sq2 = *(const float4*)&alf[w][16 + 4 * hp];
  float4 sq3 = *(const float4*)&alf[w][24 + 4 * hp];
  float* pb2 = partO + ((size_t)(half * 24 + bh) * 2048) * 64;
#pragma unroll
  for (int dt = 0; dt < 2; ++dt) {
#pragma unroll
    for (int i = 0; i < 4; ++i) {
      float4 sqv = (i == 0) ? sq0 : (i == 1) ? sq1 : (i == 2) ? sq2 : sq3;
#pragma unroll
      for (int rq = 0; rq < 4; ++rq) {
        int row = q0 + 8 * i + 4 * hp + rq;
        pb2[(size_t)row * 64 + dt * 32 + l31] = accd[dt][4 * i + rq] * ((const float*)&sqv)[rq];
      }
    }
  }
}

// ---------------- merge partials + policy[q]=0 self-diagonal -----------------
__global__ __launch_bounds__(256) void merge_kernel(const float* __restrict__ partO,
                                                    const float* __restrict__ partlm,
                                                    const float* __restrict__ vs,
                                                    const float* __restrict__ policy,
                                                    const u16* __restrict__ qkv,
                                                    u16* __restrict__ o) {
  int rr = blockIdx.x * 4 + (threadIdx.x >> 6);
  int lane = threadIdx.x & 63;
  int bh = rr >> 11, q = rr & 2047;
  int b = bh / NHEAD, h = bh % NHEAD;
  const float* O1 = partO + ((size_t)bh * 2048 + q) * 64;
  const float* O2 = partO + ((size_t)(24 + bh) * 2048 + q) * 64;
  float2 lm1 = ((const float2*)partlm)[(size_t)bh * 2048 + q];
  float2 lm2 = ((const float2*)partlm)[(size_t)(24 + bh) * 2048 + q];
  float ms = fmaxf(lm1.y, lm2.y);
  float w1 = exp2f(lm1.y - ms), w2 = exp2f(lm2.y - ms);
  float num_d = 0.f, den_d = 0.f;
  if (policy[b * NN + q] == 0.f) {
    const u16* rowp = qkv + (size_t)(b * NN + q) * 2304 + h * 64 + lane;
    float qd = bf2f(rowp[0]);
    float kd = bf2f(rowp[CC]);
    float vv = bf2f(rowp[2 * CC]);
    float dp = qd * kd;
#pragma unroll
    for (int of = 1; of < 64; of <<= 1) dp += __shfl_xor(dp, of);
    float e = exp2f(dp * 0.18033688f - ms);
    num_d = e * vv;
    den_d = e;
  }
  float den = lm1.x * w1 + lm2.x * w2 + den_d + 1e-6f;
  float vsv = vs[bh * 64 + lane] + vs[1536 + bh * 64 + lane] +
              vs[3072 + bh * 64 + lane] + vs[4608 + bh * 64 + lane];
  float num = O1[lane] * w1 + O2[lane] * w2 + num_d + (1e-6f / 2048.f) * vsv;
  o[((size_t)(b * NN + q)) * CC + h * 64 + lane] = tobf(num / den);
}

extern "C" void kernel_launch(void* const* d_in, const int* in_sizes, int n_in,
                              void* d_out, int out_size, void* d_ws, size_t ws_size,
                              hipStream_t stream) {
  const float* x = (const float*)d_in[0];
  const float* policy = (const float*)d_in[1];
  const float* ln1g = (const float*)d_in[2];
  const float* ln1b = (const float*)d_in[3];
  const float* qkvw = (const float*)d_in[4];
  const float* projw = (const float*)d_in[5];
  const float* projb = (const float*)d_in[6];
  const float* ln2g = (const float*)d_in[7];
  const float* ln2b = (const float*)d_in[8];
  const float* fc1w = (const float*)d_in[9];
  const float* fc1b = (const float*)d_in[10];
  const float* fc2w = (const float*)d_in[11];
  const float* fc2b = (const float*)d_in[12];
  float* out = (float*)d_out;

  char* ws = (char*)d_ws;
  size_t off = 0;
  auto alloc = [&](size_t bytes) {
    void* p = ws + off;
    off = (off + bytes + 255) & ~(size_t)255;
    return p;
  };
  u16* wq = (u16*)alloc((size_t)2304 * 768 * 2);
  u16* wp = (u16*)alloc((size_t)768 * 768 * 2);
  u16* w1 = (u16*)alloc((size_t)3072 * 768 * 2);
  u16* w2 = (u16*)alloc((size_t)768 * 3072 * 2);
  u16* hbuf = (u16*)alloc((size_t)4096 * 768 * 2);
  u16* obuf = (u16*)alloc((size_t)4096 * 768 * 2);
  u16* qkv = (u16*)alloc((size_t)4096 * 2304 * 2);
  float* vs = (float*)alloc((size_t)4 * 24 * 64 * 4);
  int* ncbuf = (int*)alloc(2 * sizeof(int));
  int* idxbuf = (int*)alloc((size_t)2 * NN * sizeof(int));
  size_t unionOff = off;
  float* partO = (float*)alloc((size_t)2 * 24 * 2048 * 64 * 4);
  float* partlm = (float*)alloc((size_t)2 * 24 * 2048 * 2 * 4);
  float* x1 = (float*)(ws + unionOff);  // overlaps partO/partlm (dead after proj)
  u16* ckv = hbuf;                      // hbuf+obuf region: alive gather->attn only
  u16* f1 = obuf;                       // obuf+qkv region: both dead by FC1 time

  cvt4_kernel<<<6912, 256, 0, stream>>>(qkvw, projw, fc1w, fc2w, wq, wp, w1, w2);

  ln_kernel<<<1024, 256, 0, stream>>>(x, ln1g, ln1b, hbuf);
  gemm_kernel<128, 1, 0, 0, 0><<<dim3(32, 18), 256, 0, stream>>>(
      hbuf, wq, nullptr, nullptr, qkv, 4096, 2304, 768);
  vsum_kernel<<<dim3(24, 4), 256, 0, stream>>>(qkv, vs);
  scan_kernel<<<2, 256, 0, stream>>>(policy, ncbuf, idxbuf);
  gather_kernel<<<dim3(1536, 2), 256, 0, stream>>>(qkv, ncbuf, idxbuf, ckv);
  attn32_kernel<<<dim3(32, 24), 256, 0, stream>>>(qkv, ckv, ncbuf, partO, partlm);
  merge_kernel<<<12288, 256, 0, stream>>>(partO, partlm, vs, policy, qkv, obuf);
  gemm_kernel<64, 0, 1, 0, 1><<<dim3(64, 6), 256, 0, stream>>>(
      obuf, wp, projb, x, x1, 4096, 768, 768);
  ln_kernel<<<1024, 256, 0, stream>>>(x1, ln2g, ln2b, hbuf);
  gemm_kernel<128, 1, 1, 1, 0><<<dim3(32, 24), 256, 0, stream>>>(
      hbuf, w1, fc1b, nullptr, f1, 4096, 3072, 768);
  gemm_kernel<64, 0, 1, 0, 1><<<dim3(64, 6), 256, 0, stream>>>(
      f1, w2, fc2b, x1, out, 4096, 768, 3072);
}

// Round 11
// 243.226 us; speedup vs baseline: 1.0057x; 1.0057x over previous
//
#include <hip/hip_runtime.h>

typedef unsigned short u16;
typedef unsigned int u32;
typedef float f32x4 __attribute__((ext_vector_type(4)));
typedef float f32x16 __attribute__((ext_vector_type(16)));
typedef __bf16 bf16x8 __attribute__((ext_vector_type(8)));
typedef u16 u16x4v __attribute__((ext_vector_type(4)));
typedef u32 u32x2 __attribute__((ext_vector_type(2)));
typedef u32 u32x4 __attribute__((ext_vector_type(4)));

#define NHEAD 12
#define NN 2048
#define CC 768

#define GLOBAL_AS __attribute__((address_space(1)))
#define LDS_AS __attribute__((address_space(3)))

__device__ __forceinline__ u16 tobf(float f) {
  __bf16 h = (__bf16)f;
  return __builtin_bit_cast(u16, h);
}
__device__ __forceinline__ float bf2f(u16 h) {
  u32 u = ((u32)h) << 16;
  return __builtin_bit_cast(float, u);
}
__device__ __forceinline__ u32 cvtpk(float lo, float hi) {
  u32 r;
  asm("v_cvt_pk_bf16_f32 %0, %1, %2" : "=v"(r) : "v"(lo), "v"(hi));
  return r;
}
__device__ __forceinline__ void plswap(u32& a, u32& b) {
  asm volatile("v_permlane32_swap_b32 %0, %1" : "+v"(a), "+v"(b));
}
__device__ __forceinline__ void plswapf(float& a, float& b) {
  asm volatile("v_permlane32_swap_b32 %0, %1" : "+v"(a), "+v"(b));
}
// exact-erf GELU via A&S 7.1.26 (|err| <= 1.5e-7, far below bf16 ulp)
__device__ __forceinline__ float gelu_erf(float v) {
  float y = fabsf(v) * 0.70710678118654752f;
  float t = __builtin_amdgcn_rcpf(fmaf(0.3275911f, y, 1.f));
  float p = fmaf(1.061405429f, t, -1.453152027f);
  p = fmaf(p, t, 1.421413741f);
  p = fmaf(p, t, -0.284496736f);
  p = fmaf(p, t, 0.254829592f);
  p = p * t;
  float e = __builtin_amdgcn_exp2f(-y * y * 1.44269504f);
  float er = fmaf(-p, e, 1.f);
  er = (v < 0.f) ? -er : er;
  return 0.5f * v * (1.f + er);
}

// ---------------- fused fp32 -> bf16 convert of all 4 weights ----------------
#define N4_QKV 442368
#define N4_PROJ 147456
#define N4_FC 589824
__global__ __launch_bounds__(256) void cvt4_kernel(
    const float* __restrict__ a, const float* __restrict__ b,
    const float* __restrict__ c, const float* __restrict__ d,
    u16* __restrict__ oa, u16* __restrict__ ob, u16* __restrict__ oc,
    u16* __restrict__ od) {
  int i = blockIdx.x * 256 + threadIdx.x;
  const float* src;
  u16* dst;
  if (i < N4_QKV) {
    src = a; dst = oa;
  } else if (i < N4_QKV + N4_PROJ) {
    i -= N4_QKV; src = b; dst = ob;
  } else if (i < N4_QKV + N4_PROJ + N4_FC) {
    i -= N4_QKV + N4_PROJ; src = c; dst = oc;
  } else {
    i -= N4_QKV + N4_PROJ + N4_FC; src = d; dst = od;
    if (i >= N4_FC) return;
  }
  float4 v = ((const float4*)src)[i];
  u16x4v o = {tobf(v.x), tobf(v.y), tobf(v.z), tobf(v.w)};
  ((u16x4v*)dst)[i] = o;
}

// ---------------- LayerNorm: f32 in -> bf16 out (wave per row) ----------------
__global__ __launch_bounds__(256) void ln_kernel(const float* __restrict__ x,
                                                 const float* __restrict__ gw,
                                                 const float* __restrict__ bw,
                                                 u16* __restrict__ out) {
  int row = blockIdx.x * 4 + (threadIdx.x >> 6);
  int lane = threadIdx.x & 63;
  const float* xr = x + (size_t)row * CC + lane * 12;
  float v[12];
  *(float4*)&v[0] = *(const float4*)(xr + 0);
  *(float4*)&v[4] = *(const float4*)(xr + 4);
  *(float4*)&v[8] = *(const float4*)(xr + 8);
  float s = 0.f, sq = 0.f;
#pragma unroll
  for (int j = 0; j < 12; ++j) { s += v[j]; sq += v[j] * v[j]; }
#pragma unroll
  for (int o = 1; o < 64; o <<= 1) { s += __shfl_xor(s, o); sq += __shfl_xor(sq, o); }
  float mean = s * (1.f / CC);
  float var = sq * (1.f / CC) - mean * mean;
  float rs = rsqrtf(var + 1e-5f);
  u16 ob[12];
#pragma unroll
  for (int j = 0; j < 12; ++j) {
    int c = lane * 12 + j;
    ob[j] = tobf((v[j] - mean) * rs * gw[c] + bw[c]);
  }
  u32* orow = (u32*)(out + (size_t)row * CC + lane * 12);
#pragma unroll
  for (int j = 0; j < 6; ++j) orow[j] = (u32)ob[2 * j] | ((u32)ob[2 * j + 1] << 16);
}

// ---------------- bf16 MFMA GEMM: C[M,N] = A[M,K] @ Bw[N,K]^T ----------------
// Single-buffer staging (r9 structure) + LDS-staged coalesced epilogue:
// acc -> bias/GELU -> swizzled LDS C-tile -> dwordx4 stores (+float4 residual).
template <int BM, int OB, int HASB, int ACT, int RES>
__global__ __launch_bounds__(256) void gemm_kernel(
    const u16* __restrict__ A, const u16* __restrict__ Bw,
    const float* __restrict__ bias, const float* __restrict__ res,
    void* __restrict__ Cout, int M, int N, int K) {
  constexpr int MW = BM / 2;
  constexpr int MF = MW / 16;
  constexpr int STAGE_B = BM * 64 * 2 + 128 * 64 * 2;
  constexpr int EPI_B = BM * 128 * (OB ? 2 : 4);
  constexpr int SMEM_B = (STAGE_B > EPI_B) ? STAGE_B : EPI_B;
  __shared__ __align__(16) u16 smem[SMEM_B / 2];
  u16* Alds = smem;
  u16* Blds = smem + BM * 64;
  const int tid = threadIdx.x;
  const int lane = tid & 63, wave = tid >> 6;
  const int l15 = lane & 15, g = lane >> 4;
  const int nx = gridDim.x;
  const int flat = blockIdx.y * nx + blockIdx.x;
  const int cpx = (nx * gridDim.y) >> 3;
  const int swz = (flat & 7) * cpx + (flat >> 3);
  const int bm = (swz % nx) * BM, bn = (swz / nx) * 128;
  const int wm = (wave >> 1) * MW, wn = (wave & 1) * 64;
  f32x4 acc[MF][4] = {};

  for (int kt = 0; kt < K; kt += 64) {
#pragma unroll
    for (int i = 0; i < BM / 32; ++i) {
      int ob_ = i * 4096 + wave * 1024;
      int lb = ob_ + lane * 16;
      int row = lb >> 7;
      int cb = (lb & 127) ^ ((row & 7) << 4);
      const u16* sa = A + (size_t)(bm + row) * K + kt + (cb >> 1);
      __builtin_amdgcn_global_load_lds((const GLOBAL_AS void*)sa,
                                       (LDS_AS void*)(Alds + (ob_ >> 1)), 16, 0, 0);
    }
#pragma unroll
    for (int i = 0; i < 4; ++i) {
      int ob_ = i * 4096 + wave * 1024;
      int lb = ob_ + lane * 16;
      int row = lb >> 7;
      int cb = (lb & 127) ^ ((row & 7) << 4);
      const u16* sb = Bw + (size_t)(bn + row) * K + kt + (cb >> 1);
      __builtin_amdgcn_global_load_lds((const GLOBAL_AS void*)sb,
                                       (LDS_AS void*)(Blds + (ob_ >> 1)), 16, 0, 0);
    }
    __syncthreads();
#pragma unroll
    for (int ks = 0; ks < 2; ++ks) {
      bf16x8 af[MF], bfr[4];
#pragma unroll
      for (int mi = 0; mi < MF; ++mi) {
        int row = wm + mi * 16 + l15;
        int cb = (ks * 64 + g * 16) ^ ((row & 7) << 4);
        af[mi] = *(const bf16x8*)&Alds[row * 64 + (cb >> 1)];
      }
#pragma unroll
      for (int ni = 0; ni < 4; ++ni) {
        int row = wn + ni * 16 + l15;
        int cb = (ks * 64 + g * 16) ^ ((row & 7) << 4);
        bfr[ni] = *(const bf16x8*)&Blds[row * 64 + (cb >> 1)];
      }
#pragma unroll
      for (int mi = 0; mi < MF; ++mi)
#pragma unroll
        for (int ni = 0; ni < 4; ++ni)
          acc[mi][ni] = __builtin_amdgcn_mfma_f32_16x16x32_bf16(af[mi], bfr[ni],
                                                                acc[mi][ni], 0, 0, 0);
    }
    __syncthreads();
  }

  // ---- epilogue phase 1: acc -> (bias, GELU) -> swizzled LDS C-tile ----
  char* Clds = (char*)smem;
#pragma unroll
  for (int mi = 0; mi < MF; ++mi) {
#pragma unroll
    for (int ni = 0; ni < 4; ++ni) {
      int cl = wn + ni * 16 + l15;
      float bs = HASB ? bias[bn + cl] : 0.f;
#pragma unroll
      for (int r = 0; r < 4; ++r) {
        int rl = wm + mi * 16 + g * 4 + r;
        float v = acc[mi][ni][r] + bs;
        if (ACT) v = gelu_erf(v);
        if (OB) {
          int byte_ = rl * 256 + ((cl * 2) ^ ((rl & 7) << 4));
          *(u16*)(Clds + byte_) = tobf(v);
        } else {
          int byte_ = rl * 512 + ((cl * 4) ^ ((rl & 7) << 4));
          *(float*)(Clds + byte_) = v;
        }
      }
    }
  }
  __syncthreads();
  // ---- epilogue phase 2: coalesced dwordx4 stores (+float4 residual) ----
  constexpr int ROWB = OB ? 256 : 512;  // bytes per 128-col row
  constexpr int CPR = ROWB / 16;        // 16B chunks per row
  constexpr int NITER = BM * CPR / 256;
#pragma unroll
  for (int i = 0; i < NITER; ++i) {
    int c = i * 256 + tid;
    int rl = c / CPR;
    int cb = (c % CPR) * 16;
    int sb = rl * ROWB + (cb ^ ((rl & 7) << 4));
    uint4 val = *(const uint4*)(Clds + sb);
    if (OB) {
      *(uint4*)((u16*)Cout + (size_t)(bm + rl) * N + bn + (cb >> 1)) = val;
    } else {
      float4 v4 = __builtin_bit_cast(float4, val);
      if (RES) {
        float4 r4 = *(const float4*)(res + (size_t)(bm + rl) * N + bn + (cb >> 2));
        v4.x += r4.x; v4.y += r4.y; v4.z += r4.z; v4.w += r4.w;
      }
      *(float4*)((float*)Cout + (size_t)(bm + rl) * N + bn + (cb >> 2)) = v4;
    }
  }
}

// ---------------- Vsum: vs[q4][bh][d] = partial sums of V (ALL keys) ---------
__global__ __launch_bounds__(256) void vsum_kernel(const u16* __restrict__ qkv,
                                                   float* __restrict__ vs) {
  int bh = blockIdx.x, q4 = blockIdx.y;
  int b = bh / NHEAD, h = bh % NHEAD;
  int d = threadIdx.x & 63, part = threadIdx.x >> 6;
  float s = 0.f;
  for (int n = q4 * 512 + part; n < q4 * 512 + 512; n += 4)
    s += bf2f(qkv[(size_t)(b * NN + n) * 2304 + 2 * CC + h * 64 + d]);
  __shared__ float red[256];
  red[threadIdx.x] = s;
  __syncthreads();
  if (threadIdx.x < 64) {
    float t = red[threadIdx.x] + red[threadIdx.x + 64] + red[threadIdx.x + 128] +
              red[threadIdx.x + 192];
    vs[q4 * (24 * 64) + bh * 64 + threadIdx.x] = t;
  }
}

// ---------------- policy compaction: deterministic prefix-scan ---------------
__global__ __launch_bounds__(256) void scan_kernel(const float* __restrict__ policy,
                                                   int* __restrict__ ncbuf,
                                                   int* __restrict__ idxbuf) {
  int b = blockIdx.x, tid = threadIdx.x;
  float pv[8];
  *(float4*)&pv[0] = *(const float4*)&policy[b * NN + tid * 8];
  *(float4*)&pv[4] = *(const float4*)&policy[b * NN + tid * 8 + 4];
  int cnt = 0;
#pragma unroll
  for (int j = 0; j < 8; ++j) cnt += (pv[j] != 0.f) ? 1 : 0;
  __shared__ int sc[256];
  sc[tid] = cnt;
  __syncthreads();
  for (int off = 1; off < 256; off <<= 1) {
    int v = sc[tid];
    int add = (tid >= off) ? sc[tid - off] : 0;
    __syncthreads();
    sc[tid] = v + add;
    __syncthreads();
  }
  int base = sc[tid] - cnt;
#pragma unroll
  for (int j = 0; j < 8; ++j) {
    if (pv[j] != 0.f) idxbuf[b * NN + base++] = tid * 8 + j;
  }
  if (tid == 255) ncbuf[b] = sc[255];
}

// ---------------- gather compacted K,V rows (zero the pad tile) --------------
__global__ __launch_bounds__(256) void gather_kernel(const u16* __restrict__ qkv,
                                                     const int* __restrict__ ncbuf,
                                                     const int* __restrict__ idxbuf,
                                                     u16* __restrict__ ckv) {
  int b = blockIdx.y;
  int nc = ncbuf[b];
  int ncp = (nc + 127) & ~127;
  int c = blockIdx.x * 256 + threadIdx.x;  // 16B chunk id; 192 chunks/row
  int j = c / 192, col = (c % 192) * 8;
  if (j >= ncp) return;
  uint4 val = {0, 0, 0, 0};
  if (j < nc) {
    int src = idxbuf[b * NN + j];
    val = *(const uint4*)&qkv[(size_t)(b * NN + src) * 2304 + CC + col];
  }
  *(uint4*)&ckv[(size_t)(b * NN + j) * 1536 + col] = val;
}

// ---------------- Flash attention on COMPACTED keys --------------------------
#define SCL2E 0.18033688f /* 0.125 * log2(e) */
#define TRRD(dst, addr, OFF) \
  asm volatile("ds_read_b64_tr_b16 %0, %1 offset:" OFF : "=v"(dst) : "v"(addr))

__global__ __launch_bounds__(256) void attn32_kernel(const u16* __restrict__ qkv,
                                                     const u16* __restrict__ ckv,
                                                     const int* __restrict__ ncbuf,
                                                     float* __restrict__ partO,
                                                     float* __restrict__ partlm) {
  __shared__ __align__(16) u16 Klds[2][4096];  // [key][d] XOR-swizzled rows
  __shared__ __align__(16) u16 Vlds[2][4096];  // subtiled for tr-reads
  __shared__ float alf[4][32];
  const int bh = blockIdx.y, b = bh / NHEAD, h = bh % NHEAD;
  const int qt = blockIdx.x >> 1, half = blockIdx.x & 1;
  const int tid = threadIdx.x, lane = tid & 63, w = tid >> 6;
  const int l31 = lane & 31, hp = lane >> 5, b4 = (lane >> 4) & 1;
  const int q0 = qt * 128 + w * 32;
  const int nc = ncbuf[b];
  const int ncp = (nc + 127) & ~127;
  const int nh = ncp >> 1;      // keys per half (multiple of 64)
  const int nt = nh >> 6;       // 64-key tiles per half
  const int kv0 = half * nh;
  const size_t adv = (size_t)64 * 1536;

  bf16x8 qf0, qf1, qf2, qf3;
  {
    const u16* qp = qkv + (size_t)(b * NN + q0 + l31) * 2304 + h * 64 + 8 * hp;
#pragma unroll
    for (int ds = 0; ds < 4; ++ds) {
      bf16x8 r = *(const bf16x8*)(qp + ds * 16);
      bf16x8 o;
#pragma unroll
      for (int j = 0; j < 8; ++j) o[j] = (__bf16)((float)r[j] * SCL2E);
      if (ds == 0) qf0 = o; else if (ds == 1) qf1 = o; else if (ds == 2) qf2 = o; else qf3 = o;
    }
  }

  const u16* ksrc[2];
  const u16* vsrcp[2];
#pragma unroll
  for (int c = 0; c < 2; ++c) {
    int lb = c * 4096 + w * 1024 + lane * 16;
    int row = lb >> 7;
    int cb = (lb & 127) ^ ((row & 7) << 4);
    ksrc[c] = ckv + (size_t)(b * NN + kv0 + row) * 1536 + h * 64 + (cb >> 1);
    int idx0 = (c * 256 + w * 64 + lane) * 8;
    int s0 = idx0 & 15, jj = (idx0 >> 4) & 3, b4v = (idx0 >> 6) & 1,
        pv = (idx0 >> 7) & 1, hv = (idx0 >> 8) & 1, dtv = (idx0 >> 9) & 1,
        mkv = (idx0 >> 10) & 3;
    int key = mkv * 16 + 8 * hv + 4 * pv + jj;
    int d0 = dtv * 32 + 16 * b4v + s0;
    vsrcp[c] = ckv + (size_t)(b * NN + kv0 + key) * 1536 + CC + h * 64 + d0;
  }
  auto stage = [&](int buf) {
#pragma unroll
    for (int c = 0; c < 2; ++c) {
      __builtin_amdgcn_global_load_lds((const GLOBAL_AS void*)ksrc[c],
                                       (LDS_AS void*)&Klds[buf][c * 2048 + w * 512], 16, 0, 0);
      __builtin_amdgcn_global_load_lds((const GLOBAL_AS void*)vsrcp[c],
                                       (LDS_AS void*)&Vlds[buf][c * 2048 + w * 512], 16, 0, 0);
      ksrc[c] += adv; vsrcp[c] += adv;
    }
  };

  stage(0);
  __syncthreads();

  float m_cur = -3.0e38f, m_true = -3.0e38f, l_run = 0.f;
  f32x16 accd[2] = {};
  const u32 vbase = (u32)(uintptr_t)(LDS_AS u16*)&Vlds[0][0] +
                    (u32)(2 * (lane & 15) + 128 * b4 + 512 * hp);

#pragma unroll 1
  for (int t = 0; t < nt; ++t) {
    const int cur = t & 1;
    if (t < nt - 1) stage(cur ^ 1);

    f32x16 sv0, sv1;
    {
      bf16x8 kf[4];
#pragma unroll
      for (int ds = 0; ds < 4; ++ds) {
        int row = l31;
        int cb = (32 * ds + 16 * hp) ^ ((row & 7) << 4);
        kf[ds] = *(const bf16x8*)((const char*)&Klds[cur][0] + row * 128 + cb);
      }
      f32x16 a = {};
      a = __builtin_amdgcn_mfma_f32_32x32x16_bf16(kf[0], qf0, a, 0, 0, 0);
      a = __builtin_amdgcn_mfma_f32_32x32x16_bf16(kf[1], qf1, a, 0, 0, 0);
      a = __builtin_amdgcn_mfma_f32_32x32x16_bf16(kf[2], qf2, a, 0, 0, 0);
      a = __builtin_amdgcn_mfma_f32_32x32x16_bf16(kf[3], qf3, a, 0, 0, 0);
      sv0 = a;
    }
    {
      bf16x8 kf[4];
#pragma unroll
      for (int ds = 0; ds < 4; ++ds) {
        int row = 32 + l31;
        int cb = (32 * ds + 16 * hp) ^ ((row & 7) << 4);
        kf[ds] = *(const bf16x8*)((const char*)&Klds[cur][0] + row * 128 + cb);
      }
      f32x16 a = {};
      a = __builtin_amdgcn_mfma_f32_32x32x16_bf16(kf[0], qf0, a, 0, 0, 0);
      a = __builtin_amdgcn_mfma_f32_32x32x16_bf16(kf[1], qf1, a, 0, 0, 0);
      a = __builtin_amdgcn_mfma_f32_32x32x16_bf16(kf[2], qf2, a, 0, 0, 0);
      a = __builtin_amdgcn_mfma_f32_32x32x16_bf16(kf[3], qf3, a, 0, 0, 0);
      sv1 = a;
    }

    u32x2 tr[4][2][2];
    {
      u32 vab = vbase + (u32)(cur * 8192);
      TRRD(tr[0][0][0], vab, "0");    TRRD(tr[0][0][1], vab, "256");
      TRRD(tr[0][1][0], vab, "1024"); TRRD(tr[0][1][1], vab, "1280");
      TRRD(tr[1][0][0], vab, "2048"); TRRD(tr[1][0][1], vab, "2304");
      TRRD(tr[1][1][0], vab, "3072"); TRRD(tr[1][1][1], vab, "3328");
      TRRD(tr[2][0][0], vab, "4096"); TRRD(tr[2][0][1], vab, "4352");
      TRRD(tr[3][0][0], vab, "6144"); TRRD(tr[3][0][1], vab, "6400");
      TRRD(tr[2][1][0], vab, "5120"); TRRD(tr[2][1][1], vab, "5376");
      TRRD(tr[3][1][0], vab, "7168"); TRRD(tr[3][1][1], vab, "7424");
    }

    float ta = fmaxf(fmaxf(sv0[0], sv0[1]), sv0[2]);
    float tb = fmaxf(fmaxf(sv0[3], sv0[4]), sv0[5]);
    float tc = fmaxf(fmaxf(sv0[6], sv0[7]), sv0[8]);
    float td = fmaxf(fmaxf(sv0[9], sv0[10]), sv0[11]);
    float te = fmaxf(fmaxf(sv0[12], sv0[13]), sv0[14]);
    float tf = fmaxf(fmaxf(sv0[15], sv1[0]), sv1[1]);
    float tg = fmaxf(fmaxf(sv1[2], sv1[3]), sv1[4]);
    float th = fmaxf(fmaxf(sv1[5], sv1[6]), sv1[7]);
    float ti = fmaxf(fmaxf(sv1[8], sv1[9]), sv1[10]);
    float tj = fmaxf(fmaxf(sv1[11], sv1[12]), sv1[13]);
    float tk = fmaxf(sv1[14], sv1[15]);
    float tmax = fmaxf(fmaxf(fmaxf(fmaxf(ta, tb), fmaxf(tc, td)),
                             fmaxf(fmaxf(te, tf), fmaxf(tg, th))),
                       fmaxf(fmaxf(ti, tj), tk));
    {
      float t1 = tmax, t2 = tmax;
      plswapf(t1, t2);
      tmax = fmaxf(t1, t2);
    }
    m_true = fmaxf(m_true, tmax);
    const bool defer = __all(tmax <= m_cur + 8.f);
    const float m_new = defer ? m_cur : fmaxf(m_cur, tmax);

    const int thr = nc - (kv0 + t * 64);
    float ev[32];
#pragma unroll
    for (int kt = 0; kt < 2; ++kt) {
#pragma unroll
      for (int i = 0; i < 4; ++i) {
#pragma unroll
        for (int rq = 0; rq < 4; ++rq) {
          int r = 4 * i + rq;
          int kidx = kt * 32 + 8 * i + 4 * hp + rq;
          float sval = kt ? sv1[r] : sv0[r];
          float e = __builtin_amdgcn_exp2f(sval - m_new);
          ev[kt * 16 + r] = (kidx < thr) ? e : 0.f;
        }
      }
    }
    u32 wv[16];
#pragma unroll
    for (int j = 0; j < 16; ++j) wv[j] = cvtpk(ev[2 * j], ev[2 * j + 1]);
    float ps[16];
#pragma unroll
    for (int j = 0; j < 16; ++j)
      ps[j] = __builtin_bit_cast(float, wv[j] << 16) +
              __builtin_bit_cast(float, wv[j] & 0xffff0000u);
#pragma unroll
    for (int s = 8; s > 0; s >>= 1)
#pragma unroll
      for (int j = 0; j < s; ++j) ps[j] += ps[j + s];
    float psum = ps[0];
    {
      float s1 = psum, s2 = psum;
      plswapf(s1, s2);
      psum = s1 + s2;
    }
    if (!defer) {
      float alpha = __builtin_amdgcn_exp2f(m_cur - m_new);
      l_run = l_run * alpha + psum;
      m_cur = m_new;
      if (lane < 32) alf[w][lane] = alpha;
      float4 aq0 = *(const float4*)&alf[w][4 * hp];
      float4 aq1 = *(const float4*)&alf[w][8 + 4 * hp];
      float4 aq2 = *(const float4*)&alf[w][16 + 4 * hp];
      float4 aq3 = *(const float4*)&alf[w][24 + 4 * hp];
#pragma unroll
      for (int dt = 0; dt < 2; ++dt) {
#pragma unroll
        for (int rq = 0; rq < 4; ++rq) {
          accd[dt][0 + rq] *= ((const float*)&aq0)[rq];
          accd[dt][4 + rq] *= ((const float*)&aq1)[rq];
          accd[dt][8 + rq] *= ((const float*)&aq2)[rq];
          accd[dt][12 + rq] *= ((const float*)&aq3)[rq];
        }
      }
    } else {
      l_run += psum;
    }

    u32 PK[4][4];
#pragma unroll
    for (int mk = 0; mk < 4; ++mk) {
      int bw_ = 8 * (mk >> 1) + 4 * (mk & 1);
      PK[mk][0] = wv[bw_ + 0];
      PK[mk][1] = wv[bw_ + 1];
      PK[mk][2] = wv[bw_ + 2];
      PK[mk][3] = wv[bw_ + 3];
      plswap(PK[mk][2], PK[mk][0]);
      plswap(PK[mk][3], PK[mk][1]);
    }

    asm volatile("s_waitcnt lgkmcnt(0)" ::: "memory");
    __builtin_amdgcn_sched_barrier(0);

#pragma unroll
    for (int mk = 0; mk < 4; ++mk) {
      u32x4 pk4 = {PK[mk][0], PK[mk][1], PK[mk][2], PK[mk][3]};
      bf16x8 pf = __builtin_bit_cast(bf16x8, pk4);
#pragma unroll
      for (int dt = 0; dt < 2; ++dt) {
        u32x4 vv = {tr[mk][dt][0].x, tr[mk][dt][0].y, tr[mk][dt][1].x, tr[mk][dt][1].y};
        bf16x8 vf = __builtin_bit_cast(bf16x8, vv);
        accd[dt] = __builtin_amdgcn_mfma_f32_32x32x16_bf16(pf, vf, accd[dt], 0, 0, 0);
      }
    }
    __syncthreads();
  }

  float sr = __builtin_amdgcn_exp2f(m_cur - m_true);
  if (lane < 32) {
    alf[w][lane] = sr;
    float2 lm = {l_run * sr, m_true};
    *(float2*)&partlm[2 * ((size_t)(half * 24 + bh) * 2048 + q0 + lane)] = lm;
  }
  float4 sq0 = *(const float4*)&alf[w][4 * hp];
  float4 sq1 = *(const float4*)&alf[w][8 + 4 * hp];
  float4 sq2 = *(const float4*)&alf[w][16 + 4 * hp];
  float4 sq3 = *(const float4*)&alf[w][24 + 4 * hp];
  float* pb2 = partO + ((size_t)(half * 24 + bh) * 2048) * 64;
#pragma unroll
  for (int dt = 0; dt < 2; ++dt) {
#pragma unroll
    for (int i = 0; i < 4; ++i) {
      float4 sqv = (i == 0) ? sq0 : (i == 1) ? sq1 : (i == 2) ? sq2 : sq3;
#pragma unroll
      for (int rq = 0; rq < 4; ++rq) {
        int row = q0 + 8 * i + 4 * hp + rq;
        pb2[(size_t)row * 64 + dt * 32 + l31] = accd[dt][4 * i + rq] * ((const float*)&sqv)[rq];
      }
    }
  }
}

// ---------------- merge partials + policy[q]=0 self-diagonal -----------------
__global__ __launch_bounds__(256) void merge_kernel(const float* __restrict__ partO,
                                                    const float* __restrict__ partlm,
                                                    const float* __restrict__ vs,
                                                    const float* __restrict__ policy,
                                                    const u16* __restrict__ qkv,
                                                    u16* __restrict__ o) {
  int rr = blockIdx.x * 4 + (threadIdx.x >> 6);
  int lane = threadIdx.x & 63;
  int bh = rr >> 11, q = rr & 2047;
  int b = bh / NHEAD, h = bh % NHEAD;
  const float* O1 = partO + ((size_t)bh * 2048 + q) * 64;
  const float* O2 = partO + ((size_t)(24 + bh) * 2048 + q) * 64;
  float2 lm1 = ((const float2*)partlm)[(size_t)bh * 2048 + q];
  float2 lm2 = ((const float2*)partlm)[(size_t)(24 + bh) * 2048 + q];
  float ms = fmaxf(lm1.y, lm2.y);
  float w1 = exp2f(lm1.y - ms), w2 = exp2f(lm2.y - ms);
  float num_d = 0.f, den_d = 0.f;
  if (policy[b * NN + q] == 0.f) {
    const u16* rowp = qkv + (size_t)(b * NN + q) * 2304 + h * 64 + lane;
    float qd = bf2f(rowp[0]);
    float kd = bf2f(rowp[CC]);
    float vv = bf2f(rowp[2 * CC]);
    float dp = qd * kd;
#pragma unroll
    for (int of = 1; of < 64; of <<= 1) dp += __shfl_xor(dp, of);
    float e = exp2f(dp * 0.18033688f - ms);
    num_d = e * vv;
    den_d = e;
  }
  float den = lm1.x * w1 + lm2.x * w2 + den_d + 1e-6f;
  float vsv = vs[bh * 64 + lane] + vs[1536 + bh * 64 + lane] +
              vs[3072 + bh * 64 + lane] + vs[4608 + bh * 64 + lane];
  float num = O1[lane] * w1 + O2[lane] * w2 + num_d + (1e-6f / 2048.f) * vsv;
  o[((size_t)(b * NN + q)) * CC + h * 64 + lane] = tobf(num / den);
}

extern "C" void kernel_launch(void* const* d_in, const int* in_sizes, int n_in,
                              void* d_out, int out_size, void* d_ws, size_t ws_size,
                              hipStream_t stream) {
  const float* x = (const float*)d_in[0];
  const float* policy = (const float*)d_in[1];
  const float* ln1g = (const float*)d_in[2];
  const float* ln1b = (const float*)d_in[3];
  const float* qkvw = (const float*)d_in[4];
  const float* projw = (const float*)d_in[5];
  const float* projb = (const float*)d_in[6];
  const float* ln2g = (const float*)d_in[7];
  const float* ln2b = (const float*)d_in[8];
  const float* fc1w = (const float*)d_in[9];
  const float* fc1b = (const float*)d_in[10];
  const float* fc2w = (const float*)d_in[11];
  const float* fc2b = (const float*)d_in[12];
  float* out = (float*)d_out;

  char* ws = (char*)d_ws;
  size_t off = 0;
  auto alloc = [&](size_t bytes) {
    void* p = ws + off;
    off = (off + bytes + 255) & ~(size_t)255;
    return p;
  };
  u16* wq = (u16*)alloc((size_t)2304 * 768 * 2);
  u16* wp = (u16*)alloc((size_t)768 * 768 * 2);
  u16* w1 = (u16*)alloc((size_t)3072 * 768 * 2);
  u16* w2 = (u16*)alloc((size_t)768 * 3072 * 2);
  u16* hbuf = (u16*)alloc((size_t)4096 * 768 * 2);
  u16* obuf = (u16*)alloc((size_t)4096 * 768 * 2);
  u16* qkv = (u16*)alloc((size_t)4096 * 2304 * 2);
  float* vs = (float*)alloc((size_t)4 * 24 * 64 * 4);
  int* ncbuf = (int*)alloc(2 * sizeof(int));
  int* idxbuf = (int*)alloc((size_t)2 * NN * sizeof(int));
  size_t unionOff = off;
  float* partO = (float*)alloc((size_t)2 * 24 * 2048 * 64 * 4);
  float* partlm = (float*)alloc((size_t)2 * 24 * 2048 * 2 * 4);
  float* x1 = (float*)(ws + unionOff);  // overlaps partO/partlm (dead after proj)
  u16* ckv = hbuf;                      // hbuf+obuf region: alive gather->attn only
  u16* f1 = obuf;                       // obuf+qkv region: both dead by FC1 time

  cvt4_kernel<<<6912, 256, 0, stream>>>(qkvw, projw, fc1w, fc2w, wq, wp, w1, w2);

  ln_kernel<<<1024, 256, 0, stream>>>(x, ln1g, ln1b, hbuf);
  gemm_kernel<128, 1, 0, 0, 0><<<dim3(32, 18), 256, 0, stream>>>(
      hbuf, wq, nullptr, nullptr, qkv, 4096, 2304, 768);
  vsum_kernel<<<dim3(24, 4), 256, 0, stream>>>(qkv, vs);
  scan_kernel<<<2, 256, 0, stream>>>(policy, ncbuf, idxbuf);
  gather_kernel<<<dim3(1536, 2), 256, 0, stream>>>(qkv, ncbuf, idxbuf, ckv);
  attn32_kernel<<<dim3(32, 24), 256, 0, stream>>>(qkv, ckv, ncbuf, partO, partlm);
  merge_kernel<<<12288, 256, 0, stream>>>(partO, partlm, vs, policy, qkv, obuf);
  gemm_kernel<64, 0, 1, 0, 1><<<dim3(64, 6), 256, 0, stream>>>(
      obuf, wp, projb, x, x1, 4096, 768, 768);
  ln_kernel<<<1024, 256, 0, stream>>>(x1, ln2g, ln2b, hbuf);
  gemm_kernel<128, 1, 1, 1, 0><<<dim3(32, 24), 256, 0, stream>>>(
      hbuf, w1, fc1b, nullptr, f1, 4096, 3072, 768);
  gemm_kernel<64, 0, 1, 0, 1><<<dim3(64, 6), 256, 0, stream>>>(
      f1, w2, fc2b, x1, out, 4096, 768, 3072);
}

// Round 12
// 222.159 us; speedup vs baseline: 1.1010x; 1.0948x over previous
//
#include <hip/hip_runtime.h>

typedef unsigned short u16;
typedef unsigned int u32;
typedef float f32x4 __attribute__((ext_vector_type(4)));
typedef float f32x16 __attribute__((ext_vector_type(16)));
typedef __bf16 bf16x8 __attribute__((ext_vector_type(8)));
typedef u16 u16x4v __attribute__((ext_vector_type(4)));
typedef u32 u32x2 __attribute__((ext_vector_type(2)));
typedef u32 u32x4 __attribute__((ext_vector_type(4)));

#define NHEAD 12
#define NN 2048
#define CC 768

#define GLOBAL_AS __attribute__((address_space(1)))
#define LDS_AS __attribute__((address_space(3)))

__device__ __forceinline__ u16 tobf(float f) {
  __bf16 h = (__bf16)f;
  return __builtin_bit_cast(u16, h);
}
__device__ __forceinline__ float bf2f(u16 h) {
  u32 u = ((u32)h) << 16;
  return __builtin_bit_cast(float, u);
}
__device__ __forceinline__ u32 cvtpk(float lo, float hi) {
  u32 r;
  asm("v_cvt_pk_bf16_f32 %0, %1, %2" : "=v"(r) : "v"(lo), "v"(hi));
  return r;
}
__device__ __forceinline__ void plswap(u32& a, u32& b) {
  asm volatile("v_permlane32_swap_b32 %0, %1" : "+v"(a), "+v"(b));
}
__device__ __forceinline__ void plswapf(float& a, float& b) {
  asm volatile("v_permlane32_swap_b32 %0, %1" : "+v"(a), "+v"(b));
}
// exact-erf GELU via A&S 7.1.26 (|err| <= 1.5e-7, far below bf16 ulp)
__device__ __forceinline__ float gelu_erf(float v) {
  float y = fabsf(v) * 0.70710678118654752f;
  float t = __builtin_amdgcn_rcpf(fmaf(0.3275911f, y, 1.f));
  float p = fmaf(1.061405429f, t, -1.453152027f);
  p = fmaf(p, t, 1.421413741f);
  p = fmaf(p, t, -0.284496736f);
  p = fmaf(p, t, 0.254829592f);
  p = p * t;
  float e = __builtin_amdgcn_exp2f(-y * y * 1.44269504f);
  float er = fmaf(-p, e, 1.f);
  er = (v < 0.f) ? -er : er;
  return 0.5f * v * (1.f + er);
}

// ---------------- fused fp32 -> bf16 convert of all 4 weights ----------------
#define N4_QKV 442368
#define N4_PROJ 147456
#define N4_FC 589824
__global__ __launch_bounds__(256) void cvt4_kernel(
    const float* __restrict__ a, const float* __restrict__ b,
    const float* __restrict__ c, const float* __restrict__ d,
    u16* __restrict__ oa, u16* __restrict__ ob, u16* __restrict__ oc,
    u16* __restrict__ od) {
  int i = blockIdx.x * 256 + threadIdx.x;
  const float* src;
  u16* dst;
  if (i < N4_QKV) {
    src = a; dst = oa;
  } else if (i < N4_QKV + N4_PROJ) {
    i -= N4_QKV; src = b; dst = ob;
  } else if (i < N4_QKV + N4_PROJ + N4_FC) {
    i -= N4_QKV + N4_PROJ; src = c; dst = oc;
  } else {
    i -= N4_QKV + N4_PROJ + N4_FC; src = d; dst = od;
    if (i >= N4_FC) return;
  }
  float4 v = ((const float4*)src)[i];
  u16x4v o = {tobf(v.x), tobf(v.y), tobf(v.z), tobf(v.w)};
  ((u16x4v*)dst)[i] = o;
}

// ---------------- LayerNorm: f32 in -> bf16 out (wave per row) ----------------
__global__ __launch_bounds__(256) void ln_kernel(const float* __restrict__ x,
                                                 const float* __restrict__ gw,
                                                 const float* __restrict__ bw,
                                                 u16* __restrict__ out) {
  int row = blockIdx.x * 4 + (threadIdx.x >> 6);
  int lane = threadIdx.x & 63;
  const float* xr = x + (size_t)row * CC + lane * 12;
  float v[12];
  *(float4*)&v[0] = *(const float4*)(xr + 0);
  *(float4*)&v[4] = *(const float4*)(xr + 4);
  *(float4*)&v[8] = *(const float4*)(xr + 8);
  float s = 0.f, sq = 0.f;
#pragma unroll
  for (int j = 0; j < 12; ++j) { s += v[j]; sq += v[j] * v[j]; }
#pragma unroll
  for (int o = 1; o < 64; o <<= 1) { s += __shfl_xor(s, o); sq += __shfl_xor(sq, o); }
  float mean = s * (1.f / CC);
  float var = sq * (1.f / CC) - mean * mean;
  float rs = rsqrtf(var + 1e-5f);
  u16 ob[12];
#pragma unroll
  for (int j = 0; j < 12; ++j) {
    int c = lane * 12 + j;
    ob[j] = tobf((v[j] - mean) * rs * gw[c] + bw[c]);
  }
  u32* orow = (u32*)(out + (size_t)row * CC + lane * 12);
#pragma unroll
  for (int j = 0; j < 6; ++j) orow[j] = (u32)ob[2 * j] | ((u32)ob[2 * j + 1] << 16);
}

// ---------------- bf16 MFMA GEMM: C[M,N] = A[M,K] @ Bw[N,K]^T ----------------
// r9 structure (single-buffer, 2-barrier, scalar epilogue) with BM x BN tiles.
// Smaller tiles -> more blocks/CU (grid occupancy is the lever, r10/r11 lesson).
template <int BM, int BN, int OB, int HASB, int ACT, int RES>
__global__ __launch_bounds__(256) void gemm_kernel(
    const u16* __restrict__ A, const u16* __restrict__ Bw,
    const float* __restrict__ bias, const float* __restrict__ res,
    void* __restrict__ Cout, int M, int N, int K) {
  constexpr int MW = BM / 2;
  constexpr int MF = MW / 16;
  constexpr int NF = BN / 32;
  __shared__ __align__(16) u16 Alds[BM * 64];
  __shared__ __align__(16) u16 Blds[BN * 64];
  const int tid = threadIdx.x;
  const int lane = tid & 63, wave = tid >> 6;
  const int l15 = lane & 15, g = lane >> 4;
  const int nx = gridDim.x;
  const int flat = blockIdx.y * nx + blockIdx.x;
  const int cpx = (nx * gridDim.y) >> 3;
  const int swz = (flat & 7) * cpx + (flat >> 3);
  const int bm = (swz % nx) * BM, bn = (swz / nx) * BN;
  const int wm = (wave >> 1) * MW, wn = (wave & 1) * (BN / 2);
  f32x4 acc[MF][NF] = {};

  for (int kt = 0; kt < K; kt += 64) {
#pragma unroll
    for (int i = 0; i < BM / 32; ++i) {
      int ob_ = i * 4096 + wave * 1024;
      int lb = ob_ + lane * 16;
      int row = lb >> 7;
      int cb = (lb & 127) ^ ((row & 7) << 4);
      const u16* sa = A + (size_t)(bm + row) * K + kt + (cb >> 1);
      __builtin_amdgcn_global_load_lds((const GLOBAL_AS void*)sa,
                                       (LDS_AS void*)(Alds + (ob_ >> 1)), 16, 0, 0);
    }
#pragma unroll
    for (int i = 0; i < BN / 32; ++i) {
      int ob_ = i * 4096 + wave * 1024;
      int lb = ob_ + lane * 16;
      int row = lb >> 7;
      int cb = (lb & 127) ^ ((row & 7) << 4);
      const u16* sb = Bw + (size_t)(bn + row) * K + kt + (cb >> 1);
      __builtin_amdgcn_global_load_lds((const GLOBAL_AS void*)sb,
                                       (LDS_AS void*)(Blds + (ob_ >> 1)), 16, 0, 0);
    }
    __syncthreads();
#pragma unroll
    for (int ks = 0; ks < 2; ++ks) {
      bf16x8 af[MF], bfr[NF];
#pragma unroll
      for (int mi = 0; mi < MF; ++mi) {
        int row = wm + mi * 16 + l15;
        int cb = (ks * 64 + g * 16) ^ ((row & 7) << 4);
        af[mi] = *(const bf16x8*)&Alds[row * 64 + (cb >> 1)];
      }
#pragma unroll
      for (int ni = 0; ni < NF; ++ni) {
        int row = wn + ni * 16 + l15;
        int cb = (ks * 64 + g * 16) ^ ((row & 7) << 4);
        bfr[ni] = *(const bf16x8*)&Blds[row * 64 + (cb >> 1)];
      }
#pragma unroll
      for (int mi = 0; mi < MF; ++mi)
#pragma unroll
        for (int ni = 0; ni < NF; ++ni)
          acc[mi][ni] = __builtin_amdgcn_mfma_f32_16x16x32_bf16(af[mi], bfr[ni],
                                                                acc[mi][ni], 0, 0, 0);
    }
    __syncthreads();
  }
#pragma unroll
  for (int mi = 0; mi < MF; ++mi) {
#pragma unroll
    for (int ni = 0; ni < NF; ++ni) {
      int col = bn + wn + ni * 16 + l15;
      float bs = HASB ? bias[col] : 0.f;
#pragma unroll
      for (int r = 0; r < 4; ++r) {
        int rowm = bm + wm + mi * 16 + g * 4 + r;
        float v = acc[mi][ni][r] + bs;
        if (ACT) v = gelu_erf(v);
        if (RES) v += res[(size_t)rowm * N + col];
        if (OB)
          ((u16*)Cout)[(size_t)rowm * N + col] = tobf(v);
        else
          ((float*)Cout)[(size_t)rowm * N + col] = v;
      }
    }
  }
}

// ---------------- Vsum: vs[q4][bh][d] = partial sums of V (ALL keys) ---------
__global__ __launch_bounds__(256) void vsum_kernel(const u16* __restrict__ qkv,
                                                   float* __restrict__ vs) {
  int bh = blockIdx.x, q4 = blockIdx.y;
  int b = bh / NHEAD, h = bh % NHEAD;
  int d = threadIdx.x & 63, part = threadIdx.x >> 6;
  float s = 0.f;
  for (int n = q4 * 512 + part; n < q4 * 512 + 512; n += 4)
    s += bf2f(qkv[(size_t)(b * NN + n) * 2304 + 2 * CC + h * 64 + d]);
  __shared__ float red[256];
  red[threadIdx.x] = s;
  __syncthreads();
  if (threadIdx.x < 64) {
    float t = red[threadIdx.x] + red[threadIdx.x + 64] + red[threadIdx.x + 128] +
              red[threadIdx.x + 192];
    vs[q4 * (24 * 64) + bh * 64 + threadIdx.x] = t;
  }
}

// ---------------- policy compaction: deterministic prefix-scan ---------------
__global__ __launch_bounds__(256) void scan_kernel(const float* __restrict__ policy,
                                                   int* __restrict__ ncbuf,
                                                   int* __restrict__ idxbuf) {
  int b = blockIdx.x, tid = threadIdx.x;
  float pv[8];
  *(float4*)&pv[0] = *(const float4*)&policy[b * NN + tid * 8];
  *(float4*)&pv[4] = *(const float4*)&policy[b * NN + tid * 8 + 4];
  int cnt = 0;
#pragma unroll
  for (int j = 0; j < 8; ++j) cnt += (pv[j] != 0.f) ? 1 : 0;
  __shared__ int sc[256];
  sc[tid] = cnt;
  __syncthreads();
  for (int off = 1; off < 256; off <<= 1) {
    int v = sc[tid];
    int add = (tid >= off) ? sc[tid - off] : 0;
    __syncthreads();
    sc[tid] = v + add;
    __syncthreads();
  }
  int base = sc[tid] - cnt;
#pragma unroll
  for (int j = 0; j < 8; ++j) {
    if (pv[j] != 0.f) idxbuf[b * NN + base++] = tid * 8 + j;
  }
  if (tid == 255) ncbuf[b] = sc[255];
}

// ---------------- gather compacted K,V rows (zero the pad tile) --------------
__global__ __launch_bounds__(256) void gather_kernel(const u16* __restrict__ qkv,
                                                     const int* __restrict__ ncbuf,
                                                     const int* __restrict__ idxbuf,
                                                     u16* __restrict__ ckv) {
  int b = blockIdx.y;
  int nc = ncbuf[b];
  int ncp = (nc + 127) & ~127;
  int c = blockIdx.x * 256 + threadIdx.x;  // 16B chunk id; 192 chunks/row
  int j = c / 192, col = (c % 192) * 8;
  if (j >= ncp) return;
  uint4 val = {0, 0, 0, 0};
  if (j < nc) {
    int src = idxbuf[b * NN + j];
    val = *(const uint4*)&qkv[(size_t)(b * NN + src) * 2304 + CC + col];
  }
  *(uint4*)&ckv[(size_t)(b * NN + j) * 1536 + col] = val;
}

// ---------------- Flash attention on COMPACTED keys --------------------------
#define SCL2E 0.18033688f /* 0.125 * log2(e) */
#define TRRD(dst, addr, OFF) \
  asm volatile("ds_read_b64_tr_b16 %0, %1 offset:" OFF : "=v"(dst) : "v"(addr))

__global__ __launch_bounds__(256) void attn32_kernel(const u16* __restrict__ qkv,
                                                     const u16* __restrict__ ckv,
                                                     const int* __restrict__ ncbuf,
                                                     float* __restrict__ partO,
                                                     float* __restrict__ partlm) {
  __shared__ __align__(16) u16 Klds[2][4096];  // [key][d] XOR-swizzled rows
  __shared__ __align__(16) u16 Vlds[2][4096];  // subtiled for tr-reads
  __shared__ float alf[4][32];
  const int bh = blockIdx.y, b = bh / NHEAD, h = bh % NHEAD;
  const int qt = blockIdx.x >> 1, half = blockIdx.x & 1;
  const int tid = threadIdx.x, lane = tid & 63, w = tid >> 6;
  const int l31 = lane & 31, hp = lane >> 5, b4 = (lane >> 4) & 1;
  const int q0 = qt * 128 + w * 32;
  const int nc = ncbuf[b];
  const int ncp = (nc + 127) & ~127;
  const int nh = ncp >> 1;      // keys per half (multiple of 64)
  const int nt = nh >> 6;       // 64-key tiles per half
  const int kv0 = half * nh;
  const size_t adv = (size_t)64 * 1536;

  bf16x8 qf0, qf1, qf2, qf3;
  {
    const u16* qp = qkv + (size_t)(b * NN + q0 + l31) * 2304 + h * 64 + 8 * hp;
#pragma unroll
    for (int ds = 0; ds < 4; ++ds) {
      bf16x8 r = *(const bf16x8*)(qp + ds * 16);
      bf16x8 o;
#pragma unroll
      for (int j = 0; j < 8; ++j) o[j] = (__bf16)((float)r[j] * SCL2E);
      if (ds == 0) qf0 = o; else if (ds == 1) qf1 = o; else if (ds == 2) qf2 = o; else qf3 = o;
    }
  }

  const u16* ksrc[2];
  const u16* vsrcp[2];
#pragma unroll
  for (int c = 0; c < 2; ++c) {
    int lb = c * 4096 + w * 1024 + lane * 16;
    int row = lb >> 7;
    int cb = (lb & 127) ^ ((row & 7) << 4);
    ksrc[c] = ckv + (size_t)(b * NN + kv0 + row) * 1536 + h * 64 + (cb >> 1);
    int idx0 = (c * 256 + w * 64 + lane) * 8;
    int s0 = idx0 & 15, jj = (idx0 >> 4) & 3, b4v = (idx0 >> 6) & 1,
        pv = (idx0 >> 7) & 1, hv = (idx0 >> 8) & 1, dtv = (idx0 >> 9) & 1,
        mkv = (idx0 >> 10) & 3;
    int key = mkv * 16 + 8 * hv + 4 * pv + jj;
    int d0 = dtv * 32 + 16 * b4v + s0;
    vsrcp[c] = ckv + (size_t)(b * NN + kv0 + key) * 1536 + CC + h * 64 + d0;
  }
  auto stage = [&](int buf) {
#pragma unroll
    for (int c = 0; c < 2; ++c) {
      __builtin_amdgcn_global_load_lds((const GLOBAL_AS void*)ksrc[c],
                                       (LDS_AS void*)&Klds[buf][c * 2048 + w * 512], 16, 0, 0);
      __builtin_amdgcn_global_load_lds((const GLOBAL_AS void*)vsrcp[c],
                                       (LDS_AS void*)&Vlds[buf][c * 2048 + w * 512], 16, 0, 0);
      ksrc[c] += adv; vsrcp[c] += adv;
    }
  };

  stage(0);
  __syncthreads();

  float m_cur = -3.0e38f, m_true = -3.0e38f, l_run = 0.f;
  f32x16 accd[2] = {};
  const u32 vbase = (u32)(uintptr_t)(LDS_AS u16*)&Vlds[0][0] +
                    (u32)(2 * (lane & 15) + 128 * b4 + 512 * hp);

#pragma unroll 1
  for (int t = 0; t < nt; ++t) {
    const int cur = t & 1;
    if (t < nt - 1) stage(cur ^ 1);

    f32x16 sv0, sv1;
    {
      bf16x8 kf[4];
#pragma unroll
      for (int ds = 0; ds < 4; ++ds) {
        int row = l31;
        int cb = (32 * ds + 16 * hp) ^ ((row & 7) << 4);
        kf[ds] = *(const bf16x8*)((const char*)&Klds[cur][0] + row * 128 + cb);
      }
      f32x16 a = {};
      a = __builtin_amdgcn_mfma_f32_32x32x16_bf16(kf[0], qf0, a, 0, 0, 0);
      a = __builtin_amdgcn_mfma_f32_32x32x16_bf16(kf[1], qf1, a, 0, 0, 0);
      a = __builtin_amdgcn_mfma_f32_32x32x16_bf16(kf[2], qf2, a, 0, 0, 0);
      a = __builtin_amdgcn_mfma_f32_32x32x16_bf16(kf[3], qf3, a, 0, 0, 0);
      sv0 = a;
    }
    {
      bf16x8 kf[4];
#pragma unroll
      for (int ds = 0; ds < 4; ++ds) {
        int row = 32 + l31;
        int cb = (32 * ds + 16 * hp) ^ ((row & 7) << 4);
        kf[ds] = *(const bf16x8*)((const char*)&Klds[cur][0] + row * 128 + cb);
      }
      f32x16 a = {};
      a = __builtin_amdgcn_mfma_f32_32x32x16_bf16(kf[0], qf0, a, 0, 0, 0);
      a = __builtin_amdgcn_mfma_f32_32x32x16_bf16(kf[1], qf1, a, 0, 0, 0);
      a = __builtin_amdgcn_mfma_f32_32x32x16_bf16(kf[2], qf2, a, 0, 0, 0);
      a = __builtin_amdgcn_mfma_f32_32x32x16_bf16(kf[3], qf3, a, 0, 0, 0);
      sv1 = a;
    }

    u32x2 tr[4][2][2];
    {
      u32 vab = vbase + (u32)(cur * 8192);
      TRRD(tr[0][0][0], vab, "0");    TRRD(tr[0][0][1], vab, "256");
      TRRD(tr[0][1][0], vab, "1024"); TRRD(tr[0][1][1], vab, "1280");
      TRRD(tr[1][0][0], vab, "2048"); TRRD(tr[1][0][1], vab, "2304");
      TRRD(tr[1][1][0], vab, "3072"); TRRD(tr[1][1][1], vab, "3328");
      TRRD(tr[2][0][0], vab, "4096"); TRRD(tr[2][0][1], vab, "4352");
      TRRD(tr[3][0][0], vab, "6144"); TRRD(tr[3][0][1], vab, "6400");
      TRRD(tr[2][1][0], vab, "5120"); TRRD(tr[2][1][1], vab, "5376");
      TRRD(tr[3][1][0], vab, "7168"); TRRD(tr[3][1][1], vab, "7424");
    }

    float ta = fmaxf(fmaxf(sv0[0], sv0[1]), sv0[2]);
    float tb = fmaxf(fmaxf(sv0[3], sv0[4]), sv0[5]);
    float tc = fmaxf(fmaxf(sv0[6], sv0[7]), sv0[8]);
    float td = fmaxf(fmaxf(sv0[9], sv0[10]), sv0[11]);
    float te = fmaxf(fmaxf(sv0[12], sv0[13]), sv0[14]);
    float tf = fmaxf(fmaxf(sv0[15], sv1[0]), sv1[1]);
    float tg = fmaxf(fmaxf(sv1[2], sv1[3]), sv1[4]);
    float th = fmaxf(fmaxf(sv1[5], sv1[6]), sv1[7]);
    float ti = fmaxf(fmaxf(sv1[8], sv1[9]), sv1[10]);
    float tj = fmaxf(fmaxf(sv1[11], sv1[12]), sv1[13]);
    float tk = fmaxf(sv1[14], sv1[15]);
    float tmax = fmaxf(fmaxf(fmaxf(fmaxf(ta, tb), fmaxf(tc, td)),
                             fmaxf(fmaxf(te, tf), fmaxf(tg, th))),
                       fmaxf(fmaxf(ti, tj), tk));
    {
      float t1 = tmax, t2 = tmax;
      plswapf(t1, t2);
      tmax = fmaxf(t1, t2);
    }
    m_true = fmaxf(m_true, tmax);
    const bool defer = __all(tmax <= m_cur + 8.f);
    const float m_new = defer ? m_cur : fmaxf(m_cur, tmax);

    const int thr = nc - (kv0 + t * 64);
    float ev[32];
#pragma unroll
    for (int kt = 0; kt < 2; ++kt) {
#pragma unroll
      for (int i = 0; i < 4; ++i) {
#pragma unroll
        for (int rq = 0; rq < 4; ++rq) {
          int r = 4 * i + rq;
          int kidx = kt * 32 + 8 * i + 4 * hp + rq;
          float sval = kt ? sv1[r] : sv0[r];
          float e = __builtin_amdgcn_exp2f(sval - m_new);
          ev[kt * 16 + r] = (kidx < thr) ? e : 0.f;
        }
      }
    }
    u32 wv[16];
#pragma unroll
    for (int j = 0; j < 16; ++j) wv[j] = cvtpk(ev[2 * j], ev[2 * j + 1]);
    float ps[16];
#pragma unroll
    for (int j = 0; j < 16; ++j)
      ps[j] = __builtin_bit_cast(float, wv[j] << 16) +
              __builtin_bit_cast(float, wv[j] & 0xffff0000u);
#pragma unroll
    for (int s = 8; s > 0; s >>= 1)
#pragma unroll
      for (int j = 0; j < s; ++j) ps[j] += ps[j + s];
    float psum = ps[0];
    {
      float s1 = psum, s2 = psum;
      plswapf(s1, s2);
      psum = s1 + s2;
    }
    if (!defer) {
      float alpha = __builtin_amdgcn_exp2f(m_cur - m_new);
      l_run = l_run * alpha + psum;
      m_cur = m_new;
      if (lane < 32) alf[w][lane] = alpha;
      float4 aq0 = *(const float4*)&alf[w][4 * hp];
      float4 aq1 = *(const float4*)&alf[w][8 + 4 * hp];
      float4 aq2 = *(const float4*)&alf[w][16 + 4 * hp];
      float4 aq3 = *(const float4*)&alf[w][24 + 4 * hp];
#pragma unroll
      for (int dt = 0; dt < 2; ++dt) {
#pragma unroll
        for (int rq = 0; rq < 4; ++rq) {
          accd[dt][0 + rq] *= ((const float*)&aq0)[rq];
          accd[dt][4 + rq] *= ((const float*)&aq1)[rq];
          accd[dt][8 + rq] *= ((const float*)&aq2)[rq];
          accd[dt][12 + rq] *= ((const float*)&aq3)[rq];
        }
      }
    } else {
      l_run += psum;
    }

    u32 PK[4][4];
#pragma unroll
    for (int mk = 0; mk < 4; ++mk) {
      int bw_ = 8 * (mk >> 1) + 4 * (mk & 1);
      PK[mk][0] = wv[bw_ + 0];
      PK[mk][1] = wv[bw_ + 1];
      PK[mk][2] = wv[bw_ + 2];
      PK[mk][3] = wv[bw_ + 3];
      plswap(PK[mk][2], PK[mk][0]);
      plswap(PK[mk][3], PK[mk][1]);
    }

    asm volatile("s_waitcnt lgkmcnt(0)" ::: "memory");
    __builtin_amdgcn_sched_barrier(0);

#pragma unroll
    for (int mk = 0; mk < 4; ++mk) {
      u32x4 pk4 = {PK[mk][0], PK[mk][1], PK[mk][2], PK[mk][3]};
      bf16x8 pf = __builtin_bit_cast(bf16x8, pk4);
#pragma unroll
      for (int dt = 0; dt < 2; ++dt) {
        u32x4 vv = {tr[mk][dt][0].x, tr[mk][dt][0].y, tr[mk][dt][1].x, tr[mk][dt][1].y};
        bf16x8 vf = __builtin_bit_cast(bf16x8, vv);
        accd[dt] = __builtin_amdgcn_mfma_f32_32x32x16_bf16(pf, vf, accd[dt], 0, 0, 0);
      }
    }
    __syncthreads();
  }

  float sr = __builtin_amdgcn_exp2f(m_cur - m_true);
  if (lane < 32) {
    alf[w][lane] = sr;
    float2 lm = {l_run * sr, m_true};
    *(float2*)&partlm[2 * ((size_t)(half * 24 + bh) * 2048 + q0 + lane)] = lm;
  }
  float4 sq0 = *(const float4*)&alf[w][4 * hp];
  float4 sq1 = *(const float4*)&alf[w][8 + 4 * hp];
  float4 sq2 = *(const float4*)&alf[w][16 + 4 * hp];
  float4 sq3 = *(const float4*)&alf[w][24 + 4 * hp];
  float* pb2 = partO + ((size_t)(half * 24 + bh) * 2048) * 64;
#pragma unroll
  for (int dt = 0; dt < 2; ++dt) {
#pragma unroll
    for (int i = 0; i < 4; ++i) {
      float4 sqv = (i == 0) ? sq0 : (i == 1) ? sq1 : (i == 2) ? sq2 : sq3;
#pragma unroll
      for (int rq = 0; rq < 4; ++rq) {
        int row = q0 + 8 * i + 4 * hp + rq;
        pb2[(size_t)row * 64 + dt * 32 + l31] = accd[dt][4 * i + rq] * ((const float*)&sqv)[rq];
      }
    }
  }
}

// ---------------- merge partials + policy[q]=0 self-diagonal -----------------
__global__ __launch_bounds__(256) void merge_kernel(const float* __restrict__ partO,
                                                    const float* __restrict__ partlm,
                                                    const float* __restrict__ vs,
                                                    const float* __restrict__ policy,
                                                    const u16* __restrict__ qkv,
                                                    u16* __restrict__ o) {
  int rr = blockIdx.x * 4 + (threadIdx.x >> 6);
  int lane = threadIdx.x & 63;
  int bh = rr >> 11, q = rr & 2047;
  int b = bh / NHEAD, h = bh % NHEAD;
  const float* O1 = partO + ((size_t)bh * 2048 + q) * 64;
  const float* O2 = partO + ((size_t)(24 + bh) * 2048 + q) * 64;
  float2 lm1 = ((const float2*)partlm)[(size_t)bh * 2048 + q];
  float2 lm2 = ((const float2*)partlm)[(size_t)(24 + bh) * 2048 + q];
  float ms = fmaxf(lm1.y, lm2.y);
  float w1 = exp2f(lm1.y - ms), w2 = exp2f(lm2.y - ms);
  float num_d = 0.f, den_d = 0.f;
  if (policy[b * NN + q] == 0.f) {
    const u16* rowp = qkv + (size_t)(b * NN + q) * 2304 + h * 64 + lane;
    float qd = bf2f(rowp[0]);
    float kd = bf2f(rowp[CC]);
    float vv = bf2f(rowp[2 * CC]);
    float dp = qd * kd;
#pragma unroll
    for (int of = 1; of < 64; of <<= 1) dp += __shfl_xor(dp, of);
    float e = exp2f(dp * 0.18033688f - ms);
    num_d = e * vv;
    den_d = e;
  }
  float den = lm1.x * w1 + lm2.x * w2 + den_d + 1e-6f;
  float vsv = vs[bh * 64 + lane] + vs[1536 + bh * 64 + lane] +
              vs[3072 + bh * 64 + lane] + vs[4608 + bh * 64 + lane];
  float num = O1[lane] * w1 + O2[lane] * w2 + num_d + (1e-6f / 2048.f) * vsv;
  o[((size_t)(b * NN + q)) * CC + h * 64 + lane] = tobf(num / den);
}

extern "C" void kernel_launch(void* const* d_in, const int* in_sizes, int n_in,
                              void* d_out, int out_size, void* d_ws, size_t ws_size,
                              hipStream_t stream) {
  const float* x = (const float*)d_in[0];
  const float* policy = (const float*)d_in[1];
  const float* ln1g = (const float*)d_in[2];
  const float* ln1b = (const float*)d_in[3];
  const float* qkvw = (const float*)d_in[4];
  const float* projw = (const float*)d_in[5];
  const float* projb = (const float*)d_in[6];
  const float* ln2g = (const float*)d_in[7];
  const float* ln2b = (const float*)d_in[8];
  const float* fc1w = (const float*)d_in[9];
  const float* fc1b = (const float*)d_in[10];
  const float* fc2w = (const float*)d_in[11];
  const float* fc2b = (const float*)d_in[12];
  float* out = (float*)d_out;

  char* ws = (char*)d_ws;
  size_t off = 0;
  auto alloc = [&](size_t bytes) {
    void* p = ws + off;
    off = (off + bytes + 255) & ~(size_t)255;
    return p;
  };
  u16* wq = (u16*)alloc((size_t)2304 * 768 * 2);
  u16* wp = (u16*)alloc((size_t)768 * 768 * 2);
  u16* w1 = (u16*)alloc((size_t)3072 * 768 * 2);
  u16* w2 = (u16*)alloc((size_t)768 * 3072 * 2);
  u16* hbuf = (u16*)alloc((size_t)4096 * 768 * 2);
  u16* obuf = (u16*)alloc((size_t)4096 * 768 * 2);
  u16* qkv = (u16*)alloc((size_t)4096 * 2304 * 2);
  float* vs = (float*)alloc((size_t)4 * 24 * 64 * 4);
  int* ncbuf = (int*)alloc(2 * sizeof(int));
  int* idxbuf = (int*)alloc((size_t)2 * NN * sizeof(int));
  size_t unionOff = off;
  float* partO = (float*)alloc((size_t)2 * 24 * 2048 * 64 * 4);
  float* partlm = (float*)alloc((size_t)2 * 24 * 2048 * 2 * 4);
  float* x1 = (float*)(ws + unionOff);  // overlaps partO/partlm (dead after proj)
  u16* ckv = hbuf;                      // hbuf+obuf region: alive gather->attn only
  u16* f1 = obuf;                       // obuf+qkv region: both dead by FC1 time

  cvt4_kernel<<<6912, 256, 0, stream>>>(qkvw, projw, fc1w, fc2w, wq, wp, w1, w2);

  ln_kernel<<<1024, 256, 0, stream>>>(x, ln1g, ln1b, hbuf);
  gemm_kernel<64, 128, 1, 0, 0, 0><<<dim3(64, 18), 256, 0, stream>>>(
      hbuf, wq, nullptr, nullptr, qkv, 4096, 2304, 768);
  vsum_kernel<<<dim3(24, 4), 256, 0, stream>>>(qkv, vs);
  scan_kernel<<<2, 256, 0, stream>>>(policy, ncbuf, idxbuf);
  gather_kernel<<<dim3(1536, 2), 256, 0, stream>>>(qkv, ncbuf, idxbuf, ckv);
  attn32_kernel<<<dim3(32, 24), 256, 0, stream>>>(qkv, ckv, ncbuf, partO, partlm);
  merge_kernel<<<12288, 256, 0, stream>>>(partO, partlm, vs, policy, qkv, obuf);
  gemm_kernel<64, 64, 0, 1, 0, 1><<<dim3(64, 12), 256, 0, stream>>>(
      obuf, wp, projb, x, x1, 4096, 768, 768);
  ln_kernel<<<1024, 256, 0, stream>>>(x1, ln2g, ln2b, hbuf);
  gemm_kernel<64, 128, 1, 1, 1, 0><<<dim3(64, 24), 256, 0, stream>>>(
      hbuf, w1, fc1b, nullptr, f1, 4096, 3072, 768);
  gemm_kernel<64, 64, 0, 1, 0, 1><<<dim3(64, 12), 256, 0, stream>>>(
      f1, w2, fc2b, x1, out, 4096, 768, 3072);
}

// Round 13
// 214.234 us; speedup vs baseline: 1.1418x; 1.0370x over previous
//
#include <hip/hip_runtime.h>

typedef unsigned short u16;
typedef unsigned int u32;
typedef float f32x4 __attribute__((ext_vector_type(4)));
typedef float f32x16 __attribute__((ext_vector_type(16)));
typedef __bf16 bf16x8 __attribute__((ext_vector_type(8)));
typedef u16 u16x4v __attribute__((ext_vector_type(4)));
typedef u32 u32x2 __attribute__((ext_vector_type(2)));
typedef u32 u32x4 __attribute__((ext_vector_type(4)));

#define NHEAD 12
#define NN 2048
#define CC 768

#define GLOBAL_AS __attribute__((address_space(1)))
#define LDS_AS __attribute__((address_space(3)))

__device__ __forceinline__ u16 tobf(float f) {
  __bf16 h = (__bf16)f;
  return __builtin_bit_cast(u16, h);
}
__device__ __forceinline__ float bf2f(u16 h) {
  u32 u = ((u32)h) << 16;
  return __builtin_bit_cast(float, u);
}
__device__ __forceinline__ u32 cvtpk(float lo, float hi) {
  u32 r;
  asm("v_cvt_pk_bf16_f32 %0, %1, %2" : "=v"(r) : "v"(lo), "v"(hi));
  return r;
}
__device__ __forceinline__ void plswap(u32& a, u32& b) {
  asm volatile("v_permlane32_swap_b32 %0, %1" : "+v"(a), "+v"(b));
}
__device__ __forceinline__ void plswapf(float& a, float& b) {
  asm volatile("v_permlane32_swap_b32 %0, %1" : "+v"(a), "+v"(b));
}
// exact-erf GELU via A&S 7.1.26 (|err| <= 1.5e-7, far below bf16 ulp)
__device__ __forceinline__ float gelu_erf(float v) {
  float y = fabsf(v) * 0.70710678118654752f;
  float t = __builtin_amdgcn_rcpf(fmaf(0.3275911f, y, 1.f));
  float p = fmaf(1.061405429f, t, -1.453152027f);
  p = fmaf(p, t, 1.421413741f);
  p = fmaf(p, t, -0.284496736f);
  p = fmaf(p, t, 0.254829592f);
  p = p * t;
  float e = __builtin_amdgcn_exp2f(-y * y * 1.44269504f);
  float er = fmaf(-p, e, 1.f);
  er = (v < 0.f) ? -er : er;
  return 0.5f * v * (1.f + er);
}

// ---------------- fused fp32 -> bf16 convert of all 4 weights ----------------
#define N4_QKV 442368
#define N4_PROJ 147456
#define N4_FC 589824
__global__ __launch_bounds__(256) void cvt4_kernel(
    const float* __restrict__ a, const float* __restrict__ b,
    const float* __restrict__ c, const float* __restrict__ d,
    u16* __restrict__ oa, u16* __restrict__ ob, u16* __restrict__ oc,
    u16* __restrict__ od) {
  int i = blockIdx.x * 256 + threadIdx.x;
  const float* src;
  u16* dst;
  if (i < N4_QKV) {
    src = a; dst = oa;
  } else if (i < N4_QKV + N4_PROJ) {
    i -= N4_QKV; src = b; dst = ob;
  } else if (i < N4_QKV + N4_PROJ + N4_FC) {
    i -= N4_QKV + N4_PROJ; src = c; dst = oc;
  } else {
    i -= N4_QKV + N4_PROJ + N4_FC; src = d; dst = od;
    if (i >= N4_FC) return;
  }
  float4 v = ((const float4*)src)[i];
  u16x4v o = {tobf(v.x), tobf(v.y), tobf(v.z), tobf(v.w)};
  ((u16x4v*)dst)[i] = o;
}

// ---------------- LayerNorm: f32 in -> bf16 out (wave per row) ----------------
__global__ __launch_bounds__(256) void ln_kernel(const float* __restrict__ x,
                                                 const float* __restrict__ gw,
                                                 const float* __restrict__ bw,
                                                 u16* __restrict__ out) {
  int row = blockIdx.x * 4 + (threadIdx.x >> 6);
  int lane = threadIdx.x & 63;
  const float* xr = x + (size_t)row * CC + lane * 12;
  float v[12];
  *(float4*)&v[0] = *(const float4*)(xr + 0);
  *(float4*)&v[4] = *(const float4*)(xr + 4);
  *(float4*)&v[8] = *(const float4*)(xr + 8);
  float s = 0.f, sq = 0.f;
#pragma unroll
  for (int j = 0; j < 12; ++j) { s += v[j]; sq += v[j] * v[j]; }
#pragma unroll
  for (int o = 1; o < 64; o <<= 1) { s += __shfl_xor(s, o); sq += __shfl_xor(sq, o); }
  float mean = s * (1.f / CC);
  float var = sq * (1.f / CC) - mean * mean;
  float rs = rsqrtf(var + 1e-5f);
  u16 ob[12];
#pragma unroll
  for (int j = 0; j < 12; ++j) {
    int c = lane * 12 + j;
    ob[j] = tobf((v[j] - mean) * rs * gw[c] + bw[c]);
  }
  u32* orow = (u32*)(out + (size_t)row * CC + lane * 12);
#pragma unroll
  for (int j = 0; j < 6; ++j) orow[j] = (u32)ob[2 * j] | ((u32)ob[2 * j + 1] << 16);
}

// ---------------- bf16 MFMA GEMM: C[M,N] = A[M,K] @ Bw[N,K]^T ----------------
template <int BM, int BN, int OB, int HASB, int ACT, int RES>
__global__ __launch_bounds__(256) void gemm_kernel(
    const u16* __restrict__ A, const u16* __restrict__ Bw,
    const float* __restrict__ bias, const float* __restrict__ res,
    void* __restrict__ Cout, int M, int N, int K) {
  constexpr int MW = BM / 2;
  constexpr int MF = MW / 16;
  constexpr int NF = BN / 32;
  __shared__ __align__(16) u16 Alds[BM * 64];
  __shared__ __align__(16) u16 Blds[BN * 64];
  const int tid = threadIdx.x;
  const int lane = tid & 63, wave = tid >> 6;
  const int l15 = lane & 15, g = lane >> 4;
  const int nx = gridDim.x;
  const int flat = blockIdx.y * nx + blockIdx.x;
  const int cpx = (nx * gridDim.y) >> 3;
  const int swz = (flat & 7) * cpx + (flat >> 3);
  const int bm = (swz % nx) * BM, bn = (swz / nx) * BN;
  const int wm = (wave >> 1) * MW, wn = (wave & 1) * (BN / 2);
  f32x4 acc[MF][NF] = {};

  for (int kt = 0; kt < K; kt += 64) {
#pragma unroll
    for (int i = 0; i < BM / 32; ++i) {
      int ob_ = i * 4096 + wave * 1024;
      int lb = ob_ + lane * 16;
      int row = lb >> 7;
      int cb = (lb & 127) ^ ((row & 7) << 4);
      const u16* sa = A + (size_t)(bm + row) * K + kt + (cb >> 1);
      __builtin_amdgcn_global_load_lds((const GLOBAL_AS void*)sa,
                                       (LDS_AS void*)(Alds + (ob_ >> 1)), 16, 0, 0);
    }
#pragma unroll
    for (int i = 0; i < BN / 32; ++i) {
      int ob_ = i * 4096 + wave * 1024;
      int lb = ob_ + lane * 16;
      int row = lb >> 7;
      int cb = (lb & 127) ^ ((row & 7) << 4);
      const u16* sb = Bw + (size_t)(bn + row) * K + kt + (cb >> 1);
      __builtin_amdgcn_global_load_lds((const GLOBAL_AS void*)sb,
                                       (LDS_AS void*)(Blds + (ob_ >> 1)), 16, 0, 0);
    }
    __syncthreads();
#pragma unroll
    for (int ks = 0; ks < 2; ++ks) {
      bf16x8 af[MF], bfr[NF];
#pragma unroll
      for (int mi = 0; mi < MF; ++mi) {
        int row = wm + mi * 16 + l15;
        int cb = (ks * 64 + g * 16) ^ ((row & 7) << 4);
        af[mi] = *(const bf16x8*)&Alds[row * 64 + (cb >> 1)];
      }
#pragma unroll
      for (int ni = 0; ni < NF; ++ni) {
        int row = wn + ni * 16 + l15;
        int cb = (ks * 64 + g * 16) ^ ((row & 7) << 4);
        bfr[ni] = *(const bf16x8*)&Blds[row * 64 + (cb >> 1)];
      }
#pragma unroll
      for (int mi = 0; mi < MF; ++mi)
#pragma unroll
        for (int ni = 0; ni < NF; ++ni)
          acc[mi][ni] = __builtin_amdgcn_mfma_f32_16x16x32_bf16(af[mi], bfr[ni],
                                                                acc[mi][ni], 0, 0, 0);
    }
    __syncthreads();
  }
#pragma unroll
  for (int mi = 0; mi < MF; ++mi) {
#pragma unroll
    for (int ni = 0; ni < NF; ++ni) {
      int col = bn + wn + ni * 16 + l15;
      float bs = HASB ? bias[col] : 0.f;
#pragma unroll
      for (int r = 0; r < 4; ++r) {
        int rowm = bm + wm + mi * 16 + g * 4 + r;
        float v = acc[mi][ni][r] + bs;
        if (ACT) v = gelu_erf(v);
        if (RES) v += res[(size_t)rowm * N + col];
        if (OB)
          ((u16*)Cout)[(size_t)rowm * N + col] = tobf(v);
        else
          ((float*)Cout)[(size_t)rowm * N + col] = v;
      }
    }
  }
}

// ---------------- Vsum: vs[q4][bh][d] = partial sums of V (ALL keys) ---------
__global__ __launch_bounds__(256) void vsum_kernel(const u16* __restrict__ qkv,
                                                   float* __restrict__ vs) {
  int bh = blockIdx.x, q4 = blockIdx.y;
  int b = bh / NHEAD, h = bh % NHEAD;
  int d = threadIdx.x & 63, part = threadIdx.x >> 6;
  float s = 0.f;
  for (int n = q4 * 512 + part; n < q4 * 512 + 512; n += 4)
    s += bf2f(qkv[(size_t)(b * NN + n) * 2304 + 2 * CC + h * 64 + d]);
  __shared__ float red[256];
  red[threadIdx.x] = s;
  __syncthreads();
  if (threadIdx.x < 64) {
    float t = red[threadIdx.x] + red[threadIdx.x + 64] + red[threadIdx.x + 128] +
              red[threadIdx.x + 192];
    vs[q4 * (24 * 64) + bh * 64 + threadIdx.x] = t;
  }
}

// ---------------- policy compaction: deterministic prefix-scan ---------------
__global__ __launch_bounds__(256) void scan_kernel(const float* __restrict__ policy,
                                                   int* __restrict__ ncbuf,
                                                   int* __restrict__ idxbuf) {
  int b = blockIdx.x, tid = threadIdx.x;
  float pv[8];
  *(float4*)&pv[0] = *(const float4*)&policy[b * NN + tid * 8];
  *(float4*)&pv[4] = *(const float4*)&policy[b * NN + tid * 8 + 4];
  int cnt = 0;
#pragma unroll
  for (int j = 0; j < 8; ++j) cnt += (pv[j] != 0.f) ? 1 : 0;
  __shared__ int sc[256];
  sc[tid] = cnt;
  __syncthreads();
  for (int off = 1; off < 256; off <<= 1) {
    int v = sc[tid];
    int add = (tid >= off) ? sc[tid - off] : 0;
    __syncthreads();
    sc[tid] = v + add;
    __syncthreads();
  }
  int base = sc[tid] - cnt;
#pragma unroll
  for (int j = 0; j < 8; ++j) {
    if (pv[j] != 0.f) idxbuf[b * NN + base++] = tid * 8 + j;
  }
  if (tid == 255) ncbuf[b] = sc[255];
}

// ---------------- gather compacted K,V rows (zero the pad tile) --------------
__global__ __launch_bounds__(256) void gather_kernel(const u16* __restrict__ qkv,
                                                     const int* __restrict__ ncbuf,
                                                     const int* __restrict__ idxbuf,
                                                     u16* __restrict__ ckv) {
  int b = blockIdx.y;
  int nc = ncbuf[b];
  int ncp = (nc + 127) & ~127;
  int c = blockIdx.x * 256 + threadIdx.x;  // 16B chunk id; 192 chunks/row
  int j = c / 192, col = (c % 192) * 8;
  if (j >= ncp) return;
  uint4 val = {0, 0, 0, 0};
  if (j < nc) {
    int src = idxbuf[b * NN + j];
    val = *(const uint4*)&qkv[(size_t)(b * NN + src) * 2304 + CC + col];
  }
  *(uint4*)&ckv[(size_t)(b * NN + j) * 1536 + col] = val;
}

// ---------------- Flash attention on COMPACTED keys, full range per block ----
// 2 waves x 32 q-rows = 64 q/block; each block walks ALL compacted keys.
// K,V staged once per block (shared by both waves); direct bf16 output with
// fused eps-term + policy[q]=0 self-diagonal epilogue (no merge kernel).
#define SCL2E 0.18033688f /* 0.125 * log2(e) */
#define TRRD(dst, addr, OFF) \
  asm volatile("ds_read_b64_tr_b16 %0, %1 offset:" OFF : "=v"(dst) : "v"(addr))

__global__ __launch_bounds__(128) void attn32_kernel(const u16* __restrict__ qkv,
                                                     const u16* __restrict__ ckv,
                                                     const int* __restrict__ ncbuf,
                                                     const float* __restrict__ policy,
                                                     const float* __restrict__ vsum,
                                                     u16* __restrict__ o) {
  __shared__ __align__(16) u16 Klds[2][4096];  // [key][d] XOR-swizzled rows
  __shared__ __align__(16) u16 Vlds[2][4096];  // subtiled for tr-reads
  __shared__ float alf[2][32];                 // alpha broadcast
  __shared__ float4 alfe[2][32];               // epilogue (l*sr, ed, sr)
  const int bh = blockIdx.y, b = bh / NHEAD, h = bh % NHEAD;
  const int tid = threadIdx.x, lane = tid & 63, w = tid >> 6;
  const int l31 = lane & 31, hp = lane >> 5, b4 = (lane >> 4) & 1;
  const int q0 = blockIdx.x * 64 + w * 32;
  const int nc = ncbuf[b];
  const int ncp = (nc + 127) & ~127;
  const int nt = ncp >> 6;  // 64-key tiles (even)
  const size_t adv = (size_t)64 * 1536;

  // ---- Q fragments (B-operand), scale pre-folded, persistent ----
  bf16x8 qf0, qf1, qf2, qf3;
  {
    const u16* qp = qkv + (size_t)(b * NN + q0 + l31) * 2304 + h * 64 + 8 * hp;
#pragma unroll
    for (int ds = 0; ds < 4; ++ds) {
      bf16x8 r = *(const bf16x8*)(qp + ds * 16);
      bf16x8 oo;
#pragma unroll
      for (int j = 0; j < 8; ++j) oo[j] = (__bf16)((float)r[j] * SCL2E);
      if (ds == 0) qf0 = oo; else if (ds == 1) qf1 = oo; else if (ds == 2) qf2 = oo; else qf3 = oo;
    }
  }

  // ---- cooperative staging sources (coalesced K, subtiled V); c=0..3/wave ----
  const u16* ksrc[4];
  const u16* vsrcp[4];
#pragma unroll
  for (int c = 0; c < 4; ++c) {
    int L = c * 128 + w * 64 + lane;
    int lb = L * 16;
    int row = lb >> 7;
    int cb = (lb & 127) ^ ((row & 7) << 4);
    ksrc[c] = ckv + (size_t)(b * NN + row) * 1536 + h * 64 + (cb >> 1);
    int idx0 = L * 8;
    int s0 = idx0 & 15, jj = (idx0 >> 4) & 3, b4v = (idx0 >> 6) & 1,
        pv = (idx0 >> 7) & 1, hv = (idx0 >> 8) & 1, dtv = (idx0 >> 9) & 1,
        mkv = (idx0 >> 10) & 3;
    int key = mkv * 16 + 8 * hv + 4 * pv + jj;
    int d0 = dtv * 32 + 16 * b4v + s0;
    vsrcp[c] = ckv + (size_t)(b * NN + key) * 1536 + CC + h * 64 + d0;
  }
  auto stage = [&](int buf) {
#pragma unroll
    for (int c = 0; c < 4; ++c) {
      __builtin_amdgcn_global_load_lds((const GLOBAL_AS void*)ksrc[c],
                                       (LDS_AS void*)&Klds[buf][c * 1024 + w * 512], 16, 0, 0);
      __builtin_amdgcn_global_load_lds((const GLOBAL_AS void*)vsrcp[c],
                                       (LDS_AS void*)&Vlds[buf][c * 1024 + w * 512], 16, 0, 0);
      ksrc[c] += adv; vsrcp[c] += adv;
    }
  };

  stage(0);
  __syncthreads();

  float m_cur = -3.0e38f, m_true = -3.0e38f, l_run = 0.f;
  f32x16 accd[2] = {};
  const u32 vbase = (u32)(uintptr_t)(LDS_AS u16*)&Vlds[0][0] +
                    (u32)(2 * (lane & 15) + 128 * b4 + 512 * hp);

#pragma unroll 1
  for (int t = 0; t < nt; ++t) {
    const int cur = t & 1;
    if (t < nt - 1) stage(cur ^ 1);

    f32x16 sv0, sv1;
    {
      bf16x8 kf[4];
#pragma unroll
      for (int ds = 0; ds < 4; ++ds) {
        int row = l31;
        int cb = (32 * ds + 16 * hp) ^ ((row & 7) << 4);
        kf[ds] = *(const bf16x8*)((const char*)&Klds[cur][0] + row * 128 + cb);
      }
      f32x16 a = {};
      a = __builtin_amdgcn_mfma_f32_32x32x16_bf16(kf[0], qf0, a, 0, 0, 0);
      a = __builtin_amdgcn_mfma_f32_32x32x16_bf16(kf[1], qf1, a, 0, 0, 0);
      a = __builtin_amdgcn_mfma_f32_32x32x16_bf16(kf[2], qf2, a, 0, 0, 0);
      a = __builtin_amdgcn_mfma_f32_32x32x16_bf16(kf[3], qf3, a, 0, 0, 0);
      sv0 = a;
    }
    {
      bf16x8 kf[4];
#pragma unroll
      for (int ds = 0; ds < 4; ++ds) {
        int row = 32 + l31;
        int cb = (32 * ds + 16 * hp) ^ ((row & 7) << 4);
        kf[ds] = *(const bf16x8*)((const char*)&Klds[cur][0] + row * 128 + cb);
      }
      f32x16 a = {};
      a = __builtin_amdgcn_mfma_f32_32x32x16_bf16(kf[0], qf0, a, 0, 0, 0);
      a = __builtin_amdgcn_mfma_f32_32x32x16_bf16(kf[1], qf1, a, 0, 0, 0);
      a = __builtin_amdgcn_mfma_f32_32x32x16_bf16(kf[2], qf2, a, 0, 0, 0);
      a = __builtin_amdgcn_mfma_f32_32x32x16_bf16(kf[3], qf3, a, 0, 0, 0);
      sv1 = a;
    }

    u32x2 tr[4][2][2];
    {
      u32 vab = vbase + (u32)(cur * 8192);
      TRRD(tr[0][0][0], vab, "0");    TRRD(tr[0][0][1], vab, "256");
      TRRD(tr[0][1][0], vab, "1024"); TRRD(tr[0][1][1], vab, "1280");
      TRRD(tr[1][0][0], vab, "2048"); TRRD(tr[1][0][1], vab, "2304");
      TRRD(tr[1][1][0], vab, "3072"); TRRD(tr[1][1][1], vab, "3328");
      TRRD(tr[2][0][0], vab, "4096"); TRRD(tr[2][0][1], vab, "4352");
      TRRD(tr[3][0][0], vab, "6144"); TRRD(tr[3][0][1], vab, "6400");
      TRRD(tr[2][1][0], vab, "5120"); TRRD(tr[2][1][1], vab, "5376");
      TRRD(tr[3][1][0], vab, "7168"); TRRD(tr[3][1][1], vab, "7424");
    }

    float ta = fmaxf(fmaxf(sv0[0], sv0[1]), sv0[2]);
    float tb = fmaxf(fmaxf(sv0[3], sv0[4]), sv0[5]);
    float tc = fmaxf(fmaxf(sv0[6], sv0[7]), sv0[8]);
    float td = fmaxf(fmaxf(sv0[9], sv0[10]), sv0[11]);
    float te = fmaxf(fmaxf(sv0[12], sv0[13]), sv0[14]);
    float tf = fmaxf(fmaxf(sv0[15], sv1[0]), sv1[1]);
    float tg = fmaxf(fmaxf(sv1[2], sv1[3]), sv1[4]);
    float th = fmaxf(fmaxf(sv1[5], sv1[6]), sv1[7]);
    float ti = fmaxf(fmaxf(sv1[8], sv1[9]), sv1[10]);
    float tj = fmaxf(fmaxf(sv1[11], sv1[12]), sv1[13]);
    float tk = fmaxf(sv1[14], sv1[15]);
    float tmax = fmaxf(fmaxf(fmaxf(fmaxf(ta, tb), fmaxf(tc, td)),
                             fmaxf(fmaxf(te, tf), fmaxf(tg, th))),
                       fmaxf(fmaxf(ti, tj), tk));
    {
      float t1 = tmax, t2 = tmax;
      plswapf(t1, t2);
      tmax = fmaxf(t1, t2);
    }
    m_true = fmaxf(m_true, tmax);
    const bool defer = __all(tmax <= m_cur + 8.f);
    const float m_new = defer ? m_cur : fmaxf(m_cur, tmax);

    const int thr = nc - t * 64;
    float ev[32];
#pragma unroll
    for (int kt = 0; kt < 2; ++kt) {
#pragma unroll
      for (int i = 0; i < 4; ++i) {
#pragma unroll
        for (int rq = 0; rq < 4; ++rq) {
          int r = 4 * i + rq;
          int kidx = kt * 32 + 8 * i + 4 * hp + rq;
          float sval = kt ? sv1[r] : sv0[r];
          float e = __builtin_amdgcn_exp2f(sval - m_new);
          ev[kt * 16 + r] = (kidx < thr) ? e : 0.f;
        }
      }
    }
    u32 wv[16];
#pragma unroll
    for (int j = 0; j < 16; ++j) wv[j] = cvtpk(ev[2 * j], ev[2 * j + 1]);
    float ps[16];
#pragma unroll
    for (int j = 0; j < 16; ++j)
      ps[j] = __builtin_bit_cast(float, wv[j] << 16) +
              __builtin_bit_cast(float, wv[j] & 0xffff0000u);
#pragma unroll
    for (int s = 8; s > 0; s >>= 1)
#pragma unroll
      for (int j = 0; j < s; ++j) ps[j] += ps[j + s];
    float psum = ps[0];
    {
      float s1 = psum, s2 = psum;
      plswapf(s1, s2);
      psum = s1 + s2;
    }
    if (!defer) {
      float alpha = __builtin_amdgcn_exp2f(m_cur - m_new);
      l_run = l_run * alpha + psum;
      m_cur = m_new;
      if (lane < 32) alf[w][lane] = alpha;
      float4 aq0 = *(const float4*)&alf[w][4 * hp];
      float4 aq1 = *(const float4*)&alf[w][8 + 4 * hp];
      float4 aq2 = *(const float4*)&alf[w][16 + 4 * hp];
      float4 aq3 = *(const float4*)&alf[w][24 + 4 * hp];
#pragma unroll
      for (int dt = 0; dt < 2; ++dt) {
#pragma unroll
        for (int rq = 0; rq < 4; ++rq) {
          accd[dt][0 + rq] *= ((const float*)&aq0)[rq];
          accd[dt][4 + rq] *= ((const float*)&aq1)[rq];
          accd[dt][8 + rq] *= ((const float*)&aq2)[rq];
          accd[dt][12 + rq] *= ((const float*)&aq3)[rq];
        }
      }
    } else {
      l_run += psum;
    }

    u32 PK[4][4];
#pragma unroll
    for (int mk = 0; mk < 4; ++mk) {
      int bw_ = 8 * (mk >> 1) + 4 * (mk & 1);
      PK[mk][0] = wv[bw_ + 0];
      PK[mk][1] = wv[bw_ + 1];
      PK[mk][2] = wv[bw_ + 2];
      PK[mk][3] = wv[bw_ + 3];
      plswap(PK[mk][2], PK[mk][0]);
      plswap(PK[mk][3], PK[mk][1]);
    }

    asm volatile("s_waitcnt lgkmcnt(0)" ::: "memory");
    __builtin_amdgcn_sched_barrier(0);

#pragma unroll
    for (int mk = 0; mk < 4; ++mk) {
      u32x4 pk4 = {PK[mk][0], PK[mk][1], PK[mk][2], PK[mk][3]};
      bf16x8 pf = __builtin_bit_cast(bf16x8, pk4);
#pragma unroll
      for (int dt = 0; dt < 2; ++dt) {
        u32x4 vv = {tr[mk][dt][0].x, tr[mk][dt][0].y, tr[mk][dt][1].x, tr[mk][dt][1].y};
        bf16x8 vf = __builtin_bit_cast(bf16x8, vv);
        accd[dt] = __builtin_amdgcn_mfma_f32_32x32x16_bf16(pf, vf, accd[dt], 0, 0, 0);
      }
    }
    __syncthreads();
  }

  // ---- fused epilogue: diag + eps + normalize, direct bf16 output ----
  float sr = __builtin_amdgcn_exp2f(m_cur - m_true);
  // self-diagonal score in prescaled-log2 domain (lane l31 <-> q-row q0+l31)
  float dp;
  {
    const u16* kp = qkv + (size_t)(b * NN + q0 + l31) * 2304 + CC + h * 64 + 8 * hp;
    float acc_dp = 0.f;
#pragma unroll
    for (int ds = 0; ds < 4; ++ds) {
      bf16x8 kr = *(const bf16x8*)(kp + ds * 16);
      const bf16x8& qv = (ds == 0) ? qf0 : (ds == 1) ? qf1 : (ds == 2) ? qf2 : qf3;
#pragma unroll
      for (int j = 0; j < 8; ++j) acc_dp += (float)qv[j] * (float)kr[j];
    }
    float d2 = acc_dp;
    plswapf(acc_dp, d2);
    dp = acc_dp + d2;
  }
  float pol = policy[b * NN + q0 + l31];
  float ed = (pol == 0.f) ? __builtin_amdgcn_exp2f(dp - m_true) : 0.f;
  if (lane < 32) {
    float4 pk = {l_run * sr, ed, sr, 0.f};
    alfe[w][lane] = pk;
  }
  float vsv0 = vsum[bh * 64 + l31] + vsum[1536 + bh * 64 + l31] +
               vsum[3072 + bh * 64 + l31] + vsum[4608 + bh * 64 + l31];
  float vsv1 = vsum[bh * 64 + 32 + l31] + vsum[1536 + bh * 64 + 32 + l31] +
               vsum[3072 + bh * 64 + 32 + l31] + vsum[4608 + bh * 64 + 32 + l31];
  const float epsn = 1e-6f / (float)NN;
#pragma unroll
  for (int i = 0; i < 4; ++i) {
#pragma unroll
    for (int rq = 0; rq < 4; ++rq) {
      int r = 8 * i + 4 * hp + rq;
      float4 brd = alfe[w][r];
      const u16* vrow = qkv + (size_t)(b * NN + q0 + r) * 2304 + 2 * CC + h * 64;
      float den = brd.x + brd.y + 1e-6f;
      float rden = __builtin_amdgcn_rcpf(den);
#pragma unroll
      for (int dt = 0; dt < 2; ++dt) {
        float vval = bf2f(vrow[dt * 32 + l31]);
        float vsv = dt ? vsv1 : vsv0;
        float num = accd[dt][4 * i + rq] * brd.z + brd.y * vval + epsn * vsv;
        o[(size_t)(b * NN + q0 + r) * CC + h * 64 + dt * 32 + l31] = tobf(num * rden);
      }
    }
  }
}

extern "C" void kernel_launch(void* const* d_in, const int* in_sizes, int n_in,
                              void* d_out, int out_size, void* d_ws, size_t ws_size,
                              hipStream_t stream) {
  const float* x = (const float*)d_in[0];
  const float* policy = (const float*)d_in[1];
  const float* ln1g = (const float*)d_in[2];
  const float* ln1b = (const float*)d_in[3];
  const float* qkvw = (const float*)d_in[4];
  const float* projw = (const float*)d_in[5];
  const float* projb = (const float*)d_in[6];
  const float* ln2g = (const float*)d_in[7];
  const float* ln2b = (const float*)d_in[8];
  const float* fc1w = (const float*)d_in[9];
  const float* fc1b = (const float*)d_in[10];
  const float* fc2w = (const float*)d_in[11];
  const float* fc2b = (const float*)d_in[12];
  float* out = (float*)d_out;

  char* ws = (char*)d_ws;
  size_t off = 0;
  auto alloc = [&](size_t bytes) {
    void* p = ws + off;
    off = (off + bytes + 255) & ~(size_t)255;
    return p;
  };
  u16* wq = (u16*)alloc((size_t)2304 * 768 * 2);
  u16* wp = (u16*)alloc((size_t)768 * 768 * 2);
  u16* w1 = (u16*)alloc((size_t)3072 * 768 * 2);
  u16* w2 = (u16*)alloc((size_t)768 * 3072 * 2);
  u16* hbuf = (u16*)alloc((size_t)4096 * 768 * 2);
  u16* obuf = (u16*)alloc((size_t)4096 * 768 * 2);   // attn out; f1 spans obuf+qkv
  u16* qkv = (u16*)alloc((size_t)4096 * 2304 * 2);   // contiguous after obuf
  float* vs = (float*)alloc((size_t)4 * 24 * 64 * 4);
  int* ncbuf = (int*)alloc(2 * sizeof(int));
  int* idxbuf = (int*)alloc((size_t)2 * NN * sizeof(int));
  u16* ckv = (u16*)alloc((size_t)2 * NN * 1536 * 2);  // standalone (no aliasing)
  float* x1 = (float*)alloc((size_t)4096 * 768 * 4);
  u16* f1 = obuf;  // obuf+qkv region: both dead by FC1 time

  cvt4_kernel<<<6912, 256, 0, stream>>>(qkvw, projw, fc1w, fc2w, wq, wp, w1, w2);

  ln_kernel<<<1024, 256, 0, stream>>>(x, ln1g, ln1b, hbuf);
  gemm_kernel<64, 128, 1, 0, 0, 0><<<dim3(64, 18), 256, 0, stream>>>(
      hbuf, wq, nullptr, nullptr, qkv, 4096, 2304, 768);
  vsum_kernel<<<dim3(24, 4), 256, 0, stream>>>(qkv, vs);
  scan_kernel<<<2, 256, 0, stream>>>(policy, ncbuf, idxbuf);
  gather_kernel<<<dim3(1536, 2), 256, 0, stream>>>(qkv, ncbuf, idxbuf, ckv);
  attn32_kernel<<<dim3(32, 24), 128, 0, stream>>>(qkv, ckv, ncbuf, policy, vs, obuf);
  gemm_kernel<64, 64, 0, 1, 0, 1><<<dim3(64, 12), 256, 0, stream>>>(
      obuf, wp, projb, x, x1, 4096, 768, 768);
  ln_kernel<<<1024, 256, 0, stream>>>(x1, ln2g, ln2b, hbuf);
  gemm_kernel<64, 128, 1, 1, 1, 0><<<dim3(64, 24), 256, 0, stream>>>(
      hbuf, w1, fc1b, nullptr, f1, 4096, 3072, 768);
  gemm_kernel<64, 64, 0, 1, 0, 1><<<dim3(64, 12), 256, 0, stream>>>(
      f1, w2, fc2b, x1, out, 4096, 768, 3072);
}